// Round 7
// baseline (442.251 us; speedup 1.0000x reference)
//
#include <hip/hip_runtime.h>
#include <hip/hip_bf16.h>

// NSA forward: B=2, N=1024, D=2048, H=16, HD=128, BS=64, SEL=8, WIN=64
#define HN   16
#define HDIM 128
#define NSEQ 1024
#define NBLK 16
#define BSZ  64
#define SCALE 0.08838834764831845f
#define QKV_STR 6400   // row stride of fused qkv+gate buffer (bf16), padded to 25*256
#define KOFS 2048
#define VOFS 4096
#define GOFS 6144

typedef __attribute__((ext_vector_type(8))) short bfrag;   // 8 bf16 (4 VGPRs)
typedef __attribute__((ext_vector_type(4))) float facc;    // MFMA accumulator

__device__ __forceinline__ float bf2f(short s) {
  union { unsigned u; float f; } cv;
  cv.u = ((unsigned)(unsigned short)s) << 16;
  return cv.f;
}
__device__ __forceinline__ short f2bf(float f) {
  unsigned u = __float_as_uint(f);
  u = (u + 0x7fff + ((u >> 16) & 1)) >> 16;  // RNE
  return (short)u;
}

#define ASYNC16(gp, lp)                                                    \
  __builtin_amdgcn_global_load_lds(                                        \
      (const __attribute__((address_space(1))) void*)(gp),                 \
      (__attribute__((address_space(3))) void*)(lp), 16, 0, 0)

#define MFMA16(a, b, c) __builtin_amdgcn_mfma_f32_16x16x32_bf16(a, b, c, 0, 0, 0)

// ------------------------------------------------------------------
// prep: z=0..2 -> Wq/Wk/Wv transpose-cast into w_t rows z*2048..
//       z=3   -> Wg [2048][48] transposed + zero-padded to rows 6144..6271
//       z=4   -> x cast to bf16 (no transpose)
//       z=5   -> RoPE cos/sin table (first 1024 threadblocks-worth)
// ------------------------------------------------------------------
__global__ __launch_bounds__(256) void prep(const float* __restrict__ Wq,
                                            const float* __restrict__ Wk,
                                            const float* __restrict__ Wv,
                                            const float* __restrict__ Wg,
                                            const float* __restrict__ x,
                                            short* __restrict__ w_t,
                                            short* __restrict__ x_bf,
                                            float2* __restrict__ tbl) {
  __shared__ float tile[32][33];
  const int z = blockIdx.z;
  const int bx = blockIdx.x * 32, by = blockIdx.y * 32;
  const int tx = threadIdx.x & 31, ty = threadIdx.x >> 5;
  if (z == 5) {
    if (blockIdx.y >= 4) return;
    int i = (blockIdx.y * 64 + blockIdx.x) * 256 + threadIdx.x;  // < 65536
    int d = i & 63, n = i >> 6;
    float inv = expf(-(float)d * (9.210340371976184f / 64.0f));
    float sn, cs;
    sincosf((float)n * inv, &sn, &cs);
    tbl[i] = make_float2(cs, sn);
    return;
  }
  if (z == 4) {
#pragma unroll
    for (int i = 0; i < 4; ++i) {
      const int row = by + ty + 8 * i;
      x_bf[(size_t)row * 2048 + bx + tx] = f2bf(x[(size_t)row * 2048 + bx + tx]);
    }
    return;
  }
  if (z == 3) {
    if (blockIdx.x >= 4) return;  // only 128 dst rows
#pragma unroll
    for (int i = 0; i < 4; ++i) {
      const int c = bx + tx;
      tile[ty + 8 * i][tx] = (c < 48) ? Wg[(size_t)(by + ty + 8 * i) * 48 + c] : 0.f;
    }
    __syncthreads();
#pragma unroll
    for (int i = 0; i < 4; ++i)
      w_t[(size_t)(GOFS + bx + ty + 8 * i) * 2048 + by + tx] = f2bf(tile[tx][ty + 8 * i]);
    return;
  }
  const float* src = (z == 0) ? Wq : (z == 1) ? Wk : Wv;
#pragma unroll
  for (int i = 0; i < 4; ++i)
    tile[ty + 8 * i][tx] = src[(size_t)(by + ty + 8 * i) * 2048 + bx + tx];
  __syncthreads();
#pragma unroll
  for (int i = 0; i < 4; ++i)
    w_t[(size_t)(z * 2048 + bx + ty + 8 * i) * 2048 + by + tx] = f2bf(tile[tx][ty + 8 * i]);
}

// ------------------------------------------------------------------
// Wo transpose (reuses w_t after qkv gemm)
// ------------------------------------------------------------------
__global__ __launch_bounds__(256) void transpose_cast(const float* __restrict__ src,
                                                      short* __restrict__ dst) {
  __shared__ float tile[32][33];
  const int bx = blockIdx.x * 32, by = blockIdx.y * 32;
  const int tx = threadIdx.x & 31, ty = threadIdx.x >> 5;
#pragma unroll
  for (int i = 0; i < 4; ++i)
    tile[ty + 8 * i][tx] = src[(size_t)(by + ty + 8 * i) * 2048 + bx + tx];
  __syncthreads();
#pragma unroll
  for (int i = 0; i < 4; ++i)
    dst[(size_t)(bx + ty + 8 * i) * 2048 + by + tx] = f2bf(tile[tx][ty + 8 * i]);
}

// ------------------------------------------------------------------
// 8-phase 256x256 bf16 GEMM (T2+T3+T4+T5): C[M][N] = A[M][K]*Bt[N][K]^T
// ------------------------------------------------------------------
__global__ __launch_bounds__(512, 1) void gemm256(const short* __restrict__ A,
                                                  const short* __restrict__ Bt,
                                                  short* __restrict__ C,
                                                  int M, int N, int K) {
  __shared__ short lds[2][2][16384];  // [buf][A/B][256*64]
  const int t = threadIdx.x;
  const int l = t & 63, w = t >> 6;
  const int wm = w >> 2, wn = w & 3;
  const int lm = l & 15, hi = l >> 4;
  const int lanexor = (lm & 7) << 3;            // shorts
  const int kk0 = (hi * 8) ^ lanexor;           // ks=0 column (shorts)
  const int L = blockIdx.x;
  const int row0 = (L & 7) * 256, col0 = (L >> 3) * 256;
  const int nt = K >> 6;

  const int srow = t >> 3;
  const int scol = 8 * ((t & 7) ^ (srow & 7));
  const short* Ab = A + (size_t)(row0 + srow) * K + scol;
  const short* Bb = Bt + (size_t)(col0 + srow) * K + scol;

#define STAGE(mat, srcbase, h, tau, buf)                                     \
  {                                                                          \
    const short* g_ = (srcbase) + (size_t)(h) * 128 * K + (size_t)(tau) * 64;\
    short* d_ = &lds[buf][mat][(h) * 8192 + t * 8];                          \
    ASYNC16(g_, d_);                                                         \
    ASYNC16(g_ + (size_t)64 * K, d_ + 4096);                                 \
  }

  facc acc[8][4] = {};
  bfrag af[8], bf0[4], bf1[4];

  STAGE(0, Ab, 0, 0, 0); STAGE(0, Ab, 1, 0, 0);
  STAGE(1, Bb, 0, 0, 0); STAGE(1, Bb, 1, 0, 0);
  STAGE(1, Bb, 0, 1, 1); STAGE(1, Bb, 1, 1, 1);
  asm volatile("s_waitcnt vmcnt(4)" ::: "memory");
  __builtin_amdgcn_s_barrier();

  for (int tau = 0; tau < nt; ++tau) {
    const int c = tau & 1;
    const int tA = (tau + 1 < nt) ? tau + 1 : nt - 1;
    const int tB = (tau + 2 < nt) ? tau + 2 : nt - 1;

#define DS_A(qm)                                                             \
  _Pragma("unroll") for (int ii = 0; ii < 4; ++ii) {                         \
    const int row_ = wm * 128 + (qm) * 64 + ii * 16 + lm;                    \
    af[ii * 2 + 0] = *(const bfrag*)&lds[c][0][row_ * 64 + kk0];             \
    af[ii * 2 + 1] = *(const bfrag*)&lds[c][0][row_ * 64 + (kk0 ^ 32)];      \
  }
#define DS_B(qn, arr)                                                        \
  _Pragma("unroll") for (int jj = 0; jj < 2; ++jj) {                         \
    const int row_ = wn * 64 + (qn) * 32 + jj * 16 + lm;                     \
    arr[jj * 2 + 0] = *(const bfrag*)&lds[c][1][row_ * 64 + kk0];            \
    arr[jj * 2 + 1] = *(const bfrag*)&lds[c][1][row_ * 64 + (kk0 ^ 32)];     \
  }
#define QUAD(qm, qn, arr)                                                    \
  _Pragma("unroll") for (int ii = 0; ii < 4; ++ii)                           \
  _Pragma("unroll") for (int jj = 0; jj < 2; ++jj) {                         \
    acc[(qm)*4+ii][(qn)*2+jj] = MFMA16(af[ii*2+0], arr[jj*2+0], acc[(qm)*4+ii][(qn)*2+jj]); \
    acc[(qm)*4+ii][(qn)*2+jj] = MFMA16(af[ii*2+1], arr[jj*2+1], acc[(qm)*4+ii][(qn)*2+jj]); \
  }

    DS_A(0); DS_B(0, bf0);
    STAGE(0, Ab, 0, tA, c ^ 1);
    __builtin_amdgcn_s_barrier();
    asm volatile("s_waitcnt lgkmcnt(0)" ::: "memory");
    __builtin_amdgcn_sched_barrier(0);
    __builtin_amdgcn_s_setprio(1);
    QUAD(0, 0, bf0);
    __builtin_amdgcn_s_setprio(0);
    __builtin_amdgcn_s_barrier();

    DS_B(1, bf1);
    STAGE(0, Ab, 1, tA, c ^ 1);
    __builtin_amdgcn_s_barrier();
    asm volatile("s_waitcnt lgkmcnt(0)" ::: "memory");
    __builtin_amdgcn_sched_barrier(0);
    __builtin_amdgcn_s_setprio(1);
    QUAD(0, 1, bf1);
    __builtin_amdgcn_s_setprio(0);
    __builtin_amdgcn_s_barrier();

    DS_A(1);
    STAGE(1, Bb, 0, tB, c);
    __builtin_amdgcn_s_barrier();
    asm volatile("s_waitcnt lgkmcnt(0)" ::: "memory");
    __builtin_amdgcn_sched_barrier(0);
    __builtin_amdgcn_s_setprio(1);
    QUAD(1, 1, bf1);
    __builtin_amdgcn_s_setprio(0);
    __builtin_amdgcn_s_barrier();

    STAGE(1, Bb, 1, tB, c);
    __builtin_amdgcn_s_setprio(1);
    QUAD(1, 0, bf0);
    __builtin_amdgcn_s_setprio(0);
    asm volatile("s_waitcnt vmcnt(4)" ::: "memory");
    __builtin_amdgcn_s_barrier();
  }

#pragma unroll
  for (int i = 0; i < 8; ++i)
#pragma unroll
    for (int j = 0; j < 4; ++j)
#pragma unroll
      for (int rr = 0; rr < 4; ++rr)
        C[(size_t)(row0 + wm * 128 + i * 16 + hi * 4 + rr) * N +
          col0 + wn * 64 + j * 16 + lm] = f2bf(acc[i][j][rr]);
#undef STAGE
#undef DS_A
#undef DS_B
#undef QUAD
}

// ------------------------------------------------------------------
// bf16 MFMA GEMM (m97 128^2): C[M][N] = A[M][K] * Bt[N][K]^T (out proj)
// ------------------------------------------------------------------
__device__ __forceinline__ void store_c(float* p, float v) { *p = v; }
__device__ __forceinline__ void store_c(short* p, float v) { *p = f2bf(v); }

template <typename OT>
__global__ __launch_bounds__(256) void gemm_bf16_bt(const short* __restrict__ A,
                                                    const short* __restrict__ Bt,
                                                    OT* __restrict__ C,
                                                    int M, int N, int K) {
  __shared__ short As[128 * 32];
  __shared__ short Bs[128 * 32];
  const int t = threadIdx.x;
  const int l = t & 63, w = t >> 6;
  const int wr = w >> 1, wc = w & 1;
  const int nwg = gridDim.x;
  const int L = blockIdx.x;
  const int wg = (L & 7) * (nwg >> 3) + (L >> 3);
  const int nrow = M >> 7;
  const int row0 = (wg % nrow) * 128, col0 = (wg / nrow) * 128;
  facc acc[4][4] = {};

  const int sr = t >> 2;
  const int sk = (t & 3) * 8;
  const short* Ag0 = A + (size_t)(row0 + sr) * K + sk;
  const short* Ag1 = Ag0 + (size_t)64 * K;
  const short* Bg0 = Bt + (size_t)(col0 + sr) * K + sk;
  const short* Bg1 = Bg0 + (size_t)64 * K;
  short* la = As + t * 8;
  short* lb = Bs + t * 8;

  const int lm = l & 15;
  const int lk = (l >> 4) * 8;

  for (int k0 = 0; k0 < K; k0 += 32) {
    ASYNC16(Ag0 + k0, la);
    ASYNC16(Ag1 + k0, la + 2048);
    ASYNC16(Bg0 + k0, lb);
    ASYNC16(Bg1 + k0, lb + 2048);
    __syncthreads();
    bfrag af[4], bf[4];
#pragma unroll
    for (int i = 0; i < 4; ++i)
      af[i] = *(const bfrag*)&As[(wr * 64 + i * 16 + lm) * 32 + lk];
#pragma unroll
    for (int j = 0; j < 4; ++j)
      bf[j] = *(const bfrag*)&Bs[(wc * 64 + j * 16 + lm) * 32 + lk];
#pragma unroll
    for (int i = 0; i < 4; ++i)
#pragma unroll
      for (int j = 0; j < 4; ++j)
        acc[i][j] = MFMA16(af[i], bf[j], acc[i][j]);
    __syncthreads();
  }

  const int orow = row0 + wr * 64 + (l >> 4) * 4;
  const int ocol = col0 + wc * 64 + lm;
#pragma unroll
  for (int i = 0; i < 4; ++i)
#pragma unroll
    for (int j = 0; j < 4; ++j)
#pragma unroll
      for (int rr = 0; rr < 4; ++rr)
        store_c(&C[(size_t)(orow + i * 16 + rr) * N + ocol + j * 16], acc[i][j][rr]);
}

// ------------------------------------------------------------------
// RoPE in place on q AND k slices, table-based, 8 dims/thread
// ------------------------------------------------------------------
__global__ __launch_bounds__(256) void rope_qk(short* __restrict__ qkv,
                                               const float2* __restrict__ tbl) {
  int i = blockIdx.x * 256 + threadIdx.x;  // 524288
  int c = i & 7;
  int h = (i >> 3) & 15;
  int qk = (i >> 7) & 1;
  int n = (i >> 8) & 1023;
  int b = i >> 18;
  short* base = qkv + (size_t)(b * NSEQ + n) * QKV_STR + qk * KOFS + h * HDIM + c * 8;
  const float2* tp = tbl + n * 64 + c * 8;
  bfrag t1 = *(const bfrag*)base, t2 = *(const bfrag*)(base + 64);
  bfrag o1, o2;
#pragma unroll
  for (int j = 0; j < 8; ++j) {
    float2 cssn = tp[j];
    float a = bf2f(t1[j]), bb = bf2f(t2[j]);
    o1[j] = f2bf(a * cssn.x - bb * cssn.y);
    o2[j] = f2bf(a * cssn.y + bb * cssn.x);
  }
  *(bfrag*)base = o1;
  *(bfrag*)(base + 64) = o2;
}

// ------------------------------------------------------------------
// Block mean (roped K) -> f32 kc [b][m][h][d]
// ------------------------------------------------------------------
__global__ __launch_bounds__(256) void block_mean(const short* __restrict__ src,
                                                  float* __restrict__ dst) {
  int i = blockIdx.x * 256 + threadIdx.x;  // 65536
  int d = i & 127;
  int h = (i >> 7) & 15;
  int m = (i >> 11) & 15;
  int b = i >> 15;
  const short* p = src + (size_t)(b * NSEQ + m * BSZ) * QKV_STR + h * HDIM + d;
  float acc = 0.f;
#pragma unroll 8
  for (int j = 0; j < 64; ++j) acc += bf2f(p[(size_t)j * QKV_STR]);
  dst[i] = acc * (1.0f / 64.0f);
}

// ------------------------------------------------------------------
// V transpose -> vt[b][h][d][n], fused V block-mean -> vct[b][h][d][m]
// ------------------------------------------------------------------
__global__ __launch_bounds__(256) void v_transpose(const short* __restrict__ qkv,
                                                   short* __restrict__ vt,
                                                   short* __restrict__ vct) {
  __shared__ short tile[64][136];
  const int n0 = blockIdx.x * 64;
  const int h = blockIdx.y, b = blockIdx.z;
  const int t = threadIdx.x;
#pragma unroll
  for (int it = 0; it < 4; ++it) {
    int idx = t + 256 * it;
    int row = idx >> 4, ch = idx & 15;
    *(bfrag*)&tile[row][ch * 8] =
        *(const bfrag*)&qkv[(size_t)(b * NSEQ + n0 + row) * QKV_STR + VOFS + h * HDIM + ch * 8];
  }
  __syncthreads();
#pragma unroll
  for (int it = 0; it < 4; ++it) {
    int idx = t + 256 * it;
    int d = idx >> 3, ch = idx & 7;
    bfrag tv;
    float s = 0.f;
#pragma unroll
    for (int j = 0; j < 8; ++j) {
      tv[j] = tile[ch * 8 + j][d];
      s += bf2f(tv[j]);
    }
    *(bfrag*)&vt[(((size_t)(b * HN + h) * 128) + d) * 1024 + n0 + ch * 8] = tv;
    s += __shfl_down(s, 4);
    s += __shfl_down(s, 2);
    s += __shfl_down(s, 1);
    if ((t & 7) == 0)
      vct[(((size_t)(b * HN + h) * 128) + d) * 16 + (n0 >> 6)] = f2bf(s * (1.0f / 64.0f));
  }
}

// ------------------------------------------------------------------
// Compressed probs (bf16 pc [b][h][n][16]) + top-8 selection bitmask.
// Register-light: s[16] accumulated per 8-dim chunk.
// ------------------------------------------------------------------
__global__ __launch_bounds__(64) void cmp_sel(const short* __restrict__ qkv,
                                              const float* __restrict__ kc,
                                              short* __restrict__ pc,
                                              int* __restrict__ sel) {
  int i = blockIdx.x * 64 + threadIdx.x;  // B*H*N = 32768
  int n = i & 1023;
  int h = (i >> 10) & 15;
  int b = i >> 14;
  const short* qp = qkv + (size_t)(b * NSEQ + n) * QKV_STR + h * HDIM;
  const int nv = (n + 1) >> 6;
  float s[NBLK];
#pragma unroll
  for (int m = 0; m < NBLK; ++m) s[m] = 0.f;
  for (int d0 = 0; d0 < HDIM; d0 += 8) {
    bfrag qv = *(const bfrag*)&qp[d0];
    float qf[8];
#pragma unroll
    for (int dd = 0; dd < 8; ++dd) qf[dd] = bf2f(qv[dd]);
    for (int m = 0; m < nv; ++m) {
      const float4* kp = (const float4*)(kc + ((size_t)((b * NBLK + m) * HN + h) << 7) + d0);
      const float4 k0 = kp[0], k1 = kp[1];
      s[m] += qf[0] * k0.x + qf[1] * k0.y + qf[2] * k0.z + qf[3] * k0.w +
              qf[4] * k1.x + qf[5] * k1.y + qf[6] * k1.z + qf[7] * k1.w;
    }
  }
  float mx = -1e30f;
  for (int m = 0; m < nv; ++m) { s[m] *= SCALE; mx = fmaxf(mx, s[m]); }
  float den = 0.f;
  for (int m = 0; m < nv; ++m) { s[m] = __expf(s[m] - mx); den += s[m]; }
  const float rden = (nv > 0) ? 1.0f / den : 0.f;
  float p[NBLK];
#pragma unroll
  for (int m = 0; m < NBLK; ++m) p[m] = (m < nv) ? s[m] * rden : 0.f;
  bfrag o0, o1;
#pragma unroll
  for (int m = 0; m < 8; ++m) { o0[m] = f2bf(p[m]); o1[m] = f2bf(p[m + 8]); }
  bfrag* pout = (bfrag*)(pc + (size_t)i * 16);
  pout[0] = o0; pout[1] = o1;
  p[n >> 6] += 2.0f;
  int mask = 0;
#pragma unroll
  for (int ss = 0; ss < 8; ++ss) {
    int best = 0;
    float bv = -1e30f;
#pragma unroll
    for (int m = 0; m < NBLK; ++m)
      if (p[m] > bv) { bv = p[m]; best = m; }
    mask |= 1 << best;
    p[best] = -1e30f;
  }
  sel[i] = mask;
}

// ------------------------------------------------------------------
// MFMA attention. 2 waves per (b,h,16-row tile): active tiles split
// odd/even between waves (disjoint partial sums), combined via LDS.
// XCD-swizzled grid, heavy-first. Pipelined K loads, V hoisted.
// ------------------------------------------------------------------
__global__ __launch_bounds__(128, 4) void attn_mfma(
    const short* __restrict__ qkv, const short* __restrict__ vt,
    const short* __restrict__ vct, const short* __restrict__ pc,
    const int* __restrict__ sel, short* __restrict__ o) {
  const int fid = blockIdx.x;
  const int xcd = fid & 7;
  const int idx = fid >> 3;              // 0..255
  const int pair = (xcd << 2) | (idx & 3);
  const int rt = 63 - (idx >> 2);        // heavy tiles first
  const int h = pair & 15, b = pair >> 4;

  const int tid = threadIdx.x;
  const int wid = tid >> 6;
  const int l = tid & 63;
  const int lm = l & 15, hi = l >> 4;
  const int nbase = rt * 16;

  __shared__ short pbuf[2][2][1024];     // [wid][slc/swa][...]  (8 KB)
  float* cb = (float*)&pbuf[0][0][0];    // combine overlay, 2048 floats

  // Q A-fragments
  const short* qrow = qkv + (size_t)(b * NSEQ + nbase + lm) * QKV_STR + h * HDIM;
  bfrag qf[4];
#pragma unroll
  for (int ks = 0; ks < 4; ++ks) qf[ks] = *(const bfrag*)&qrow[32 * ks + 8 * hi];

  // selection bits
  int selrow = sel[(size_t)(b * HN + h) * NSEQ + nbase + lm];
  int uni = selrow;
#pragma unroll
  for (int m = 1; m < 16; m <<= 1) uni |= __shfl_xor(uni, m);
  int sel4[4];
#pragma unroll
  for (int rg = 0; rg < 4; ++rg) sel4[rg] = __shfl(selrow, 4 * hi + rg);

  const int thi = nbase >> 6;
  const int tlo = (nbase >= 64) ? ((nbase - 64) >> 6) : 0;
  const int wmask = (int)((2u << thi) - (1u << tlo));
  const unsigned am = (unsigned)(uni | wmask) & (unsigned)((2u << thi) - 1);

  // split active tiles alternately between the 2 waves
  unsigned amw = 0;
  {
    unsigned mm = am;
    int p = 0;
    while (mm) {
      unsigned lb = mm & (0u - mm);
      if ((p & 1) == wid) amw |= lb;
      mm ^= lb;
      ++p;
    }
  }

  facc acc_slc[8] = {}, acc_swa[8] = {};
  float ps_s[4] = {0.f, 0.f, 0.f, 0.f}, ps_w[4] = {0.f, 0.f, 0.f, 0.f};

  const short* kbase0 = qkv + (size_t)(b * NSEQ) * QKV_STR + KOFS + h * HDIM + 8 * hi;
  const short* vtb0 = vt + ((size_t)(b * HN + h) * 128) * 1024 + 8 * hi;
  short* p_slc = &pbuf[wid][0][0];
  short* p_swa = &pbuf[wid][1][0];

  int ct = -1;
  bfrag ka0, ka1, ka2, ka3;
  if (amw) {
    ct = __ffs((int)amw) - 1;
    const short* kr = kbase0 + (size_t)(ct * 64 + lm) * QKV_STR;
    ka0 = *(const bfrag*)(kr);
    ka1 = *(const bfrag*)(kr + 32);
    ka2 = *(const bfrag*)(kr + 64);
    ka3 = *(const bfrag*)(kr + 96);
  }

  while (ct >= 0) {
    const unsigned rem = amw & ~((2u << ct) - 1);
    const int nct = rem ? (__ffs((int)rem) - 1) : -1;
    const bool do_s = (uni >> ct) & 1;
    const bool do_w = (wmask >> ct) & 1;

    // ---- QK^T with streaming K prefetch
    facc sacc[4] = {};
#pragma unroll
    for (int f = 0; f < 4; ++f) {
      const int pct = (f < 3) ? ct : (nct >= 0 ? nct : ct);
      const int pfr = (f < 3) ? 16 * (f + 1) : 0;
      const short* krn = kbase0 + (size_t)(pct * 64 + pfr + lm) * QKV_STR;
      bfrag kn0 = *(const bfrag*)(krn);
      bfrag kn1 = *(const bfrag*)(krn + 32);
      bfrag kn2 = *(const bfrag*)(krn + 64);
      bfrag kn3 = *(const bfrag*)(krn + 96);
      sacc[f] = MFMA16(qf[0], ka0, sacc[f]);
      sacc[f] = MFMA16(qf[1], ka1, sacc[f]);
      sacc[f] = MFMA16(qf[2], ka2, sacc[f]);
      sacc[f] = MFMA16(qf[3], ka3, sacc[f]);
      ka0 = kn0; ka1 = kn1; ka2 = kn2; ka3 = kn3;
    }

    // ---- hoist V loads (ks=0)
    const short* vtb = vtb0 + ct * 64;
    bfrag vb0[8];
#pragma unroll
    for (int df = 0; df < 8; ++df)
      vb0[df] = *(const bfrag*)&vtb[(size_t)(16 * df + lm) * 1024];

    // ---- exp + masks + partial sums + LDS P write (XOR-swizzled)
#pragma unroll
    for (int f = 0; f < 4; ++f) {
      const int col = ct * 64 + 16 * f + lm;
#pragma unroll
      for (int rg = 0; rg < 4; ++rg) {
        const int row = nbase + 4 * hi + rg;
        float e = __expf(sacc[f][rg] * SCALE);
        e = (col <= row) ? e : 0.f;
        float es = ((sel4[rg] >> ct) & 1) ? e : 0.f;
        float ew = (row - col <= 64) ? e : 0.f;
        ps_s[rg] += es;
        ps_w[rg] += ew;
        const int srow = 4 * hi + rg;
        const int sidx = (64 * srow + 16 * f + lm) ^ ((srow & 7) << 3);
        if (do_s) p_slc[sidx] = f2bf(es);
        if (do_w) p_swa[sidx] = f2bf(ew);
      }
    }

    // ---- PV (within-wave LDS dependence orders write->read; no barrier)
    {
      const int ridx0 = (64 * lm + 8 * hi) ^ ((lm & 7) << 3);
      bfrag pas = {}, paw = {};
      if (do_s) pas = *(const bfrag*)&p_slc[ridx0];
      if (do_w) paw = *(const bfrag*)&p_swa[ridx0];
      bfrag vb1[8];
#pragma unroll
      for (int df = 0; df < 8; ++df)
        vb1[df] = *(const bfrag*)&vtb[(size_t)(16 * df + lm) * 1024 + 32];
#pragma unroll
      for (int df = 0; df < 8; ++df) {
        if (do_s) acc_slc[df] = MFMA16(pas, vb0[df], acc_slc[df]);
        if (do_w) acc_swa[df] = MFMA16(paw, vb0[df], acc_swa[df]);
      }
      const int ridx1 = (64 * lm + 8 * hi + 32) ^ ((lm & 7) << 3);
      bfrag pas1 = {}, paw1 = {};
      if (do_s) pas1 = *(const bfrag*)&p_slc[ridx1];
      if (do_w) paw1 = *(const bfrag*)&p_swa[ridx1];
#pragma unroll
      for (int df = 0; df < 8; ++df) {
        if (do_s) acc_slc[df] = MFMA16(pas1, vb1[df], acc_slc[df]);
        if (do_w) acc_swa[df] = MFMA16(paw1, vb1[df], acc_swa[df]);
      }
    }
    ct = nct;
  }

  // ---- cross-wave combine (wave1 -> wave0) via cb overlay
  __syncthreads();
  if (wid == 1) {
    float* q = cb + l * 8;
#pragma unroll
    for (int rg = 0; rg < 4; ++rg) { q[rg] = ps_s[rg]; q[4 + rg] = ps_w[rg]; }
  }
  __syncthreads();
  if (wid == 0) {
    const float* q = cb + l * 8;
#pragma unroll
    for (int rg = 0; rg < 4; ++rg) { ps_s[rg] += q[rg]; ps_w[rg] += q[4 + rg]; }
  }
  __syncthreads();
  if (wid == 1) {
    float* q = cb + l * 32;
#pragma unroll
    for (int df = 0; df < 8; ++df)
#pragma unroll
      for (int rg = 0; rg < 4; ++rg) q[df * 4 + rg] = acc_slc[df][rg];
  }
  __syncthreads();
  if (wid == 0) {
    const float* q = cb + l * 32;
#pragma unroll
    for (int df = 0; df < 8; ++df)
#pragma unroll
      for (int rg = 0; rg < 4; ++rg) acc_slc[df][rg] += q[df * 4 + rg];
  }
  __syncthreads();
  if (wid == 1) {
    float* q = cb + l * 32;
#pragma unroll
    for (int df = 0; df < 8; ++df)
#pragma unroll
      for (int rg = 0; rg < 4; ++rg) q[df * 4 + rg] = acc_swa[df][rg];
  }
  __syncthreads();
  if (wid != 0) return;
  {
    const float* q = cb + l * 32;
#pragma unroll
    for (int df = 0; df < 8; ++df)
#pragma unroll
      for (int rg = 0; rg < 4; ++rg) acc_swa[df][rg] += q[df * 4 + rg];
  }

  // ---- compressed branch: O_cmp = Pc[16x16] * Vc[16x128], K padded to 32
  facc acc_cmp[8] = {};
  {
    bfrag pa = {};
    if (hi < 2)
      pa = *(const bfrag*)&pc[((size_t)(b * HN + h) * NSEQ + nbase + lm) * 16 + 8 * hi];
#pragma unroll
    for (int df = 0; df < 8; ++df) {
      bfrag vb = {};
      if (hi < 2)
        vb = *(const bfrag*)&vct[(((size_t)(b * HN + h) * 128) + 16 * df + lm) * 16 + 8 * hi];
      acc_cmp[df] = MFMA16(pa, vb, acc_cmp[df]);
    }
  }

  // ---- denominators: reduce across the 16 col-lanes
#pragma unroll
  for (int m = 1; m < 16; m <<= 1) {
#pragma unroll
    for (int rg = 0; rg < 4; ++rg) {
      ps_s[rg] += __shfl_xor(ps_s[rg], m);
      ps_w[rg] += __shfl_xor(ps_w[rg], m);
    }
  }

  float inv_s[4], inv_w[4], gcv[4], gsv[4], gwv[4];
#pragma unroll
  for (int rg = 0; rg < 4; ++rg) {
    inv_s[rg] = 1.0f / ps_s[rg];
    inv_w[rg] = 1.0f / ps_w[rg];
    const short* gp = qkv + (size_t)(b * NSEQ + nbase + 4 * hi + rg) * QKV_STR + GOFS;
    gcv[rg] = 1.0f / (1.0f + __expf(-bf2f(gp[h])));
    gsv[rg] = 1.0f / (1.0f + __expf(-bf2f(gp[16 + h])));
    gwv[rg] = 1.0f / (1.0f + __expf(-bf2f(gp[32 + h])));
  }

  short* obase = o + (size_t)(b * NSEQ + nbase) * 2048 + h * HDIM;
#pragma unroll
  for (int df = 0; df < 8; ++df)
#pragma unroll
    for (int rg = 0; rg < 4; ++rg) {
      float val = gcv[rg] * acc_cmp[df][rg] +
                  gsv[rg] * acc_slc[df][rg] * inv_s[rg] +
                  gwv[rg] * acc_swa[df][rg] * inv_w[rg];
      obase[(size_t)(4 * hi + rg) * 2048 + 16 * df + lm] = f2bf(val);
    }
}

// ------------------------------------------------------------------
extern "C" void kernel_launch(void* const* d_in, const int* in_sizes, int n_in,
                              void* d_out, int out_size, void* d_ws, size_t ws_size,
                              hipStream_t stream) {
  const float* x  = (const float*)d_in[0];
  const float* Wq = (const float*)d_in[1];
  const float* Wk = (const float*)d_in[2];
  const float* Wv = (const float*)d_in[3];
  const float* Wg = (const float*)d_in[4];
  const float* Wo = (const float*)d_in[5];
  float* out = (float*)d_out;

  char* w = (char*)d_ws;
  short* x_bf = (short*)w;            // 8.4 MB (reused as o_bf)
  short* o_bf = x_bf;
  w += (size_t)2048 * 2048 * 2;
  short* w_t  = (short*)w;            // 26.2 MB (rows 6272..6399 unused pad)
  w += (size_t)6400 * 2048 * 2;
  short* qkv  = (short*)w;            // 26.2 MB (stride 6400; gate at 6144)
  w += (size_t)2048 * 6400 * 2;
  float* kc   = (float*)w; w += (size_t)65536 * 4;
  short* vct  = (short*)w; w += (size_t)65536 * 2;
  short* pcb  = (short*)w; w += (size_t)524288 * 2;
  int*   sel  = (int*)w;   w += (size_t)32768 * 4;
  short* vt   = (short*)w; w += (size_t)4194304 * 2;  // 8.4 MB
  float2* tbl = (float2*)w; w += (size_t)65536 * 8;   // 0.5 MB

  const dim3 blk(256);
  prep<<<dim3(64, 64, 6), blk, 0, stream>>>(Wq, Wk, Wv, Wg, x, w_t, x_bf, tbl);
  gemm256<<<200, dim3(512), 0, stream>>>(x_bf, w_t, qkv, 2048, 6400, 2048);
  rope_qk<<<2048, blk, 0, stream>>>(qkv, tbl);
  block_mean<<<256, blk, 0, stream>>>(qkv + KOFS, kc);
  v_transpose<<<dim3(16, 16, 2), blk, 0, stream>>>(qkv, vt, vct);
  cmp_sel<<<512, dim3(64), 0, stream>>>(qkv, kc, pcb, sel);
  transpose_cast<<<dim3(64, 64), blk, 0, stream>>>(Wo, w_t);
  attn_mfma<<<2048, dim3(128), 0, stream>>>(qkv, vt, vct, pcb, sel, o_bf);
  gemm_bf16_bt<float><<<256, blk, 0, stream>>>(o_bf, w_t, out, 2048, 2048, 2048);
}

// Round 8
// 411.635 us; speedup vs baseline: 1.0744x; 1.0744x over previous
//
#include <hip/hip_runtime.h>
#include <hip/hip_bf16.h>

// NSA forward: B=2, N=1024, D=2048, H=16, HD=128, BS=64, SEL=8, WIN=64
#define HN   16
#define HDIM 128
#define NSEQ 1024
#define NBLK 16
#define BSZ  64
#define SCALE 0.08838834764831845f
#define QKV_STR 6400   // row stride of fused qkv+gate buffer (bf16), padded to 25*256
#define KOFS 2048
#define VOFS 4096
#define GOFS 6144

typedef __attribute__((ext_vector_type(8))) short bfrag;   // 8 bf16 (4 VGPRs)
typedef __attribute__((ext_vector_type(4))) float facc;    // MFMA accumulator

__device__ __forceinline__ float bf2f(short s) {
  union { unsigned u; float f; } cv;
  cv.u = ((unsigned)(unsigned short)s) << 16;
  return cv.f;
}
__device__ __forceinline__ short f2bf(float f) {
  unsigned u = __float_as_uint(f);
  u = (u + 0x7fff + ((u >> 16) & 1)) >> 16;  // RNE
  return (short)u;
}

#define ASYNC16(gp, lp)                                                    \
  __builtin_amdgcn_global_load_lds(                                        \
      (const __attribute__((address_space(1))) void*)(gp),                 \
      (__attribute__((address_space(3))) void*)(lp), 16, 0, 0)

#define MFMA16(a, b, c) __builtin_amdgcn_mfma_f32_16x16x32_bf16(a, b, c, 0, 0, 0)

// ------------------------------------------------------------------
// prep: z=0..2 -> Wq/Wk/Wv transpose-cast into w_t rows z*2048..
//       z=3   -> Wg transposed + zero-padded to rows 6144..6271
//       z=4   -> x cast to bf16
//       z=5   -> RoPE cos/sin table
// ------------------------------------------------------------------
__global__ __launch_bounds__(256) void prep(const float* __restrict__ Wq,
                                            const float* __restrict__ Wk,
                                            const float* __restrict__ Wv,
                                            const float* __restrict__ Wg,
                                            const float* __restrict__ x,
                                            short* __restrict__ w_t,
                                            short* __restrict__ x_bf,
                                            float2* __restrict__ tbl) {
  __shared__ float tile[32][33];
  const int z = blockIdx.z;
  const int bx = blockIdx.x * 32, by = blockIdx.y * 32;
  const int tx = threadIdx.x & 31, ty = threadIdx.x >> 5;
  if (z == 5) {
    if (blockIdx.y >= 4) return;
    int i = (blockIdx.y * 64 + blockIdx.x) * 256 + threadIdx.x;  // < 65536
    int d = i & 63, n = i >> 6;
    float inv = expf(-(float)d * (9.210340371976184f / 64.0f));
    float sn, cs;
    sincosf((float)n * inv, &sn, &cs);
    tbl[i] = make_float2(cs, sn);
    return;
  }
  if (z == 4) {
#pragma unroll
    for (int i = 0; i < 4; ++i) {
      const int row = by + ty + 8 * i;
      x_bf[(size_t)row * 2048 + bx + tx] = f2bf(x[(size_t)row * 2048 + bx + tx]);
    }
    return;
  }
  if (z == 3) {
    if (blockIdx.x >= 4) return;  // only 128 dst rows
#pragma unroll
    for (int i = 0; i < 4; ++i) {
      const int c = bx + tx;
      tile[ty + 8 * i][tx] = (c < 48) ? Wg[(size_t)(by + ty + 8 * i) * 48 + c] : 0.f;
    }
    __syncthreads();
#pragma unroll
    for (int i = 0; i < 4; ++i)
      w_t[(size_t)(GOFS + bx + ty + 8 * i) * 2048 + by + tx] = f2bf(tile[tx][ty + 8 * i]);
    return;
  }
  const float* src = (z == 0) ? Wq : (z == 1) ? Wk : Wv;
#pragma unroll
  for (int i = 0; i < 4; ++i)
    tile[ty + 8 * i][tx] = src[(size_t)(by + ty + 8 * i) * 2048 + bx + tx];
  __syncthreads();
#pragma unroll
  for (int i = 0; i < 4; ++i)
    w_t[(size_t)(z * 2048 + bx + ty + 8 * i) * 2048 + by + tx] = f2bf(tile[tx][ty + 8 * i]);
}

// ------------------------------------------------------------------
// Wo transpose (reuses w_t after qkv gemm)
// ------------------------------------------------------------------
__global__ __launch_bounds__(256) void transpose_cast(const float* __restrict__ src,
                                                      short* __restrict__ dst) {
  __shared__ float tile[32][33];
  const int bx = blockIdx.x * 32, by = blockIdx.y * 32;
  const int tx = threadIdx.x & 31, ty = threadIdx.x >> 5;
#pragma unroll
  for (int i = 0; i < 4; ++i)
    tile[ty + 8 * i][tx] = src[(size_t)(by + ty + 8 * i) * 2048 + bx + tx];
  __syncthreads();
#pragma unroll
  for (int i = 0; i < 4; ++i)
    dst[(size_t)(bx + ty + 8 * i) * 2048 + by + tx] = f2bf(tile[tx][ty + 8 * i]);
}

// ------------------------------------------------------------------
// 8-phase 256x256 bf16 GEMM (T2+T3+T4+T5): C[M][N] = A[M][K]*Bt[N][K]^T
// ------------------------------------------------------------------
__global__ __launch_bounds__(512, 1) void gemm256(const short* __restrict__ A,
                                                  const short* __restrict__ Bt,
                                                  short* __restrict__ C,
                                                  int M, int N, int K) {
  __shared__ short lds[2][2][16384];  // [buf][A/B][256*64]
  const int t = threadIdx.x;
  const int l = t & 63, w = t >> 6;
  const int wm = w >> 2, wn = w & 3;
  const int lm = l & 15, hi = l >> 4;
  const int lanexor = (lm & 7) << 3;            // shorts
  const int kk0 = (hi * 8) ^ lanexor;           // ks=0 column (shorts)
  const int L = blockIdx.x;
  const int row0 = (L & 7) * 256, col0 = (L >> 3) * 256;
  const int nt = K >> 6;

  const int srow = t >> 3;
  const int scol = 8 * ((t & 7) ^ (srow & 7));
  const short* Ab = A + (size_t)(row0 + srow) * K + scol;
  const short* Bb = Bt + (size_t)(col0 + srow) * K + scol;

#define STAGE(mat, srcbase, h, tau, buf)                                     \
  {                                                                          \
    const short* g_ = (srcbase) + (size_t)(h) * 128 * K + (size_t)(tau) * 64;\
    short* d_ = &lds[buf][mat][(h) * 8192 + t * 8];                          \
    ASYNC16(g_, d_);                                                         \
    ASYNC16(g_ + (size_t)64 * K, d_ + 4096);                                 \
  }

  facc acc[8][4] = {};
  bfrag af[8], bf0[4], bf1[4];

  STAGE(0, Ab, 0, 0, 0); STAGE(0, Ab, 1, 0, 0);
  STAGE(1, Bb, 0, 0, 0); STAGE(1, Bb, 1, 0, 0);
  STAGE(1, Bb, 0, 1, 1); STAGE(1, Bb, 1, 1, 1);
  asm volatile("s_waitcnt vmcnt(4)" ::: "memory");
  __builtin_amdgcn_s_barrier();

  for (int tau = 0; tau < nt; ++tau) {
    const int c = tau & 1;
    const int tA = (tau + 1 < nt) ? tau + 1 : nt - 1;
    const int tB = (tau + 2 < nt) ? tau + 2 : nt - 1;

#define DS_A(qm)                                                             \
  _Pragma("unroll") for (int ii = 0; ii < 4; ++ii) {                         \
    const int row_ = wm * 128 + (qm) * 64 + ii * 16 + lm;                    \
    af[ii * 2 + 0] = *(const bfrag*)&lds[c][0][row_ * 64 + kk0];             \
    af[ii * 2 + 1] = *(const bfrag*)&lds[c][0][row_ * 64 + (kk0 ^ 32)];      \
  }
#define DS_B(qn, arr)                                                        \
  _Pragma("unroll") for (int jj = 0; jj < 2; ++jj) {                         \
    const int row_ = wn * 64 + (qn) * 32 + jj * 16 + lm;                     \
    arr[jj * 2 + 0] = *(const bfrag*)&lds[c][1][row_ * 64 + kk0];            \
    arr[jj * 2 + 1] = *(const bfrag*)&lds[c][1][row_ * 64 + (kk0 ^ 32)];     \
  }
#define QUAD(qm, qn, arr)                                                    \
  _Pragma("unroll") for (int ii = 0; ii < 4; ++ii)                           \
  _Pragma("unroll") for (int jj = 0; jj < 2; ++jj) {                         \
    acc[(qm)*4+ii][(qn)*2+jj] = MFMA16(af[ii*2+0], arr[jj*2+0], acc[(qm)*4+ii][(qn)*2+jj]); \
    acc[(qm)*4+ii][(qn)*2+jj] = MFMA16(af[ii*2+1], arr[jj*2+1], acc[(qm)*4+ii][(qn)*2+jj]); \
  }

    DS_A(0); DS_B(0, bf0);
    STAGE(0, Ab, 0, tA, c ^ 1);
    __builtin_amdgcn_s_barrier();
    asm volatile("s_waitcnt lgkmcnt(0)" ::: "memory");
    __builtin_amdgcn_sched_barrier(0);
    __builtin_amdgcn_s_setprio(1);
    QUAD(0, 0, bf0);
    __builtin_amdgcn_s_setprio(0);
    __builtin_amdgcn_s_barrier();

    DS_B(1, bf1);
    STAGE(0, Ab, 1, tA, c ^ 1);
    __builtin_amdgcn_s_barrier();
    asm volatile("s_waitcnt lgkmcnt(0)" ::: "memory");
    __builtin_amdgcn_sched_barrier(0);
    __builtin_amdgcn_s_setprio(1);
    QUAD(0, 1, bf1);
    __builtin_amdgcn_s_setprio(0);
    __builtin_amdgcn_s_barrier();

    DS_A(1);
    STAGE(1, Bb, 0, tB, c);
    __builtin_amdgcn_s_barrier();
    asm volatile("s_waitcnt lgkmcnt(0)" ::: "memory");
    __builtin_amdgcn_sched_barrier(0);
    __builtin_amdgcn_s_setprio(1);
    QUAD(1, 1, bf1);
    __builtin_amdgcn_s_setprio(0);
    __builtin_amdgcn_s_barrier();

    STAGE(1, Bb, 1, tB, c);
    __builtin_amdgcn_s_setprio(1);
    QUAD(1, 0, bf0);
    __builtin_amdgcn_s_setprio(0);
    asm volatile("s_waitcnt vmcnt(4)" ::: "memory");
    __builtin_amdgcn_s_barrier();
  }

#pragma unroll
  for (int i = 0; i < 8; ++i)
#pragma unroll
    for (int j = 0; j < 4; ++j)
#pragma unroll
      for (int rr = 0; rr < 4; ++rr)
        C[(size_t)(row0 + wm * 128 + i * 16 + hi * 4 + rr) * N +
          col0 + wn * 64 + j * 16 + lm] = f2bf(acc[i][j][rr]);
#undef STAGE
#undef DS_A
#undef DS_B
#undef QUAD
}

// ------------------------------------------------------------------
// bf16 MFMA GEMM (m97 128^2): C[M][N] = A[M][K] * Bt[N][K]^T (out proj)
// ------------------------------------------------------------------
__device__ __forceinline__ void store_c(float* p, float v) { *p = v; }
__device__ __forceinline__ void store_c(short* p, float v) { *p = f2bf(v); }

template <typename OT>
__global__ __launch_bounds__(256) void gemm_bf16_bt(const short* __restrict__ A,
                                                    const short* __restrict__ Bt,
                                                    OT* __restrict__ C,
                                                    int M, int N, int K) {
  __shared__ short As[128 * 32];
  __shared__ short Bs[128 * 32];
  const int t = threadIdx.x;
  const int l = t & 63, w = t >> 6;
  const int wr = w >> 1, wc = w & 1;
  const int nwg = gridDim.x;
  const int L = blockIdx.x;
  const int wg = (L & 7) * (nwg >> 3) + (L >> 3);
  const int nrow = M >> 7;
  const int row0 = (wg % nrow) * 128, col0 = (wg / nrow) * 128;
  facc acc[4][4] = {};

  const int sr = t >> 2;
  const int sk = (t & 3) * 8;
  const short* Ag0 = A + (size_t)(row0 + sr) * K + sk;
  const short* Ag1 = Ag0 + (size_t)64 * K;
  const short* Bg0 = Bt + (size_t)(col0 + sr) * K + sk;
  const short* Bg1 = Bg0 + (size_t)64 * K;
  short* la = As + t * 8;
  short* lb = Bs + t * 8;

  const int lm = l & 15;
  const int lk = (l >> 4) * 8;

  for (int k0 = 0; k0 < K; k0 += 32) {
    ASYNC16(Ag0 + k0, la);
    ASYNC16(Ag1 + k0, la + 2048);
    ASYNC16(Bg0 + k0, lb);
    ASYNC16(Bg1 + k0, lb + 2048);
    __syncthreads();
    bfrag af[4], bf[4];
#pragma unroll
    for (int i = 0; i < 4; ++i)
      af[i] = *(const bfrag*)&As[(wr * 64 + i * 16 + lm) * 32 + lk];
#pragma unroll
    for (int j = 0; j < 4; ++j)
      bf[j] = *(const bfrag*)&Bs[(wc * 64 + j * 16 + lm) * 32 + lk];
#pragma unroll
    for (int i = 0; i < 4; ++i)
#pragma unroll
      for (int j = 0; j < 4; ++j)
        acc[i][j] = MFMA16(af[i], bf[j], acc[i][j]);
    __syncthreads();
  }

  const int orow = row0 + wr * 64 + (l >> 4) * 4;
  const int ocol = col0 + wc * 64 + lm;
#pragma unroll
  for (int i = 0; i < 4; ++i)
#pragma unroll
    for (int j = 0; j < 4; ++j)
#pragma unroll
      for (int rr = 0; rr < 4; ++rr)
        store_c(&C[(size_t)(orow + i * 16 + rr) * N + ocol + j * 16], acc[i][j][rr]);
}

// ------------------------------------------------------------------
// RoPE in place on q AND k slices, table-based, 8 dims/thread
// ------------------------------------------------------------------
__global__ __launch_bounds__(256) void rope_qk(short* __restrict__ qkv,
                                               const float2* __restrict__ tbl) {
  int i = blockIdx.x * 256 + threadIdx.x;  // 524288
  int c = i & 7;
  int h = (i >> 3) & 15;
  int qk = (i >> 7) & 1;
  int n = (i >> 8) & 1023;
  int b = i >> 18;
  short* base = qkv + (size_t)(b * NSEQ + n) * QKV_STR + qk * KOFS + h * HDIM + c * 8;
  const float2* tp = tbl + n * 64 + c * 8;
  bfrag t1 = *(const bfrag*)base, t2 = *(const bfrag*)(base + 64);
  bfrag o1, o2;
#pragma unroll
  for (int j = 0; j < 8; ++j) {
    float2 cssn = tp[j];
    float a = bf2f(t1[j]), bb = bf2f(t2[j]);
    o1[j] = f2bf(a * cssn.x - bb * cssn.y);
    o2[j] = f2bf(a * cssn.y + bb * cssn.x);
  }
  *(bfrag*)base = o1;
  *(bfrag*)(base + 64) = o2;
}

// ------------------------------------------------------------------
// Block mean (roped K) -> f32 kc [b][m][h][d]
// ------------------------------------------------------------------
__global__ __launch_bounds__(256) void block_mean(const short* __restrict__ src,
                                                  float* __restrict__ dst) {
  int i = blockIdx.x * 256 + threadIdx.x;  // 65536
  int d = i & 127;
  int h = (i >> 7) & 15;
  int m = (i >> 11) & 15;
  int b = i >> 15;
  const short* p = src + (size_t)(b * NSEQ + m * BSZ) * QKV_STR + h * HDIM + d;
  float acc = 0.f;
#pragma unroll 8
  for (int j = 0; j < 64; ++j) acc += bf2f(p[(size_t)j * QKV_STR]);
  dst[i] = acc * (1.0f / 64.0f);
}

// ------------------------------------------------------------------
// V transpose -> vt[b][h][d][n], fused V block-mean -> vct[b][h][d][m]
// ------------------------------------------------------------------
__global__ __launch_bounds__(256) void v_transpose(const short* __restrict__ qkv,
                                                   short* __restrict__ vt,
                                                   short* __restrict__ vct) {
  __shared__ short tile[64][136];
  const int n0 = blockIdx.x * 64;
  const int h = blockIdx.y, b = blockIdx.z;
  const int t = threadIdx.x;
#pragma unroll
  for (int it = 0; it < 4; ++it) {
    int idx = t + 256 * it;
    int row = idx >> 4, ch = idx & 15;
    *(bfrag*)&tile[row][ch * 8] =
        *(const bfrag*)&qkv[(size_t)(b * NSEQ + n0 + row) * QKV_STR + VOFS + h * HDIM + ch * 8];
  }
  __syncthreads();
#pragma unroll
  for (int it = 0; it < 4; ++it) {
    int idx = t + 256 * it;
    int d = idx >> 3, ch = idx & 7;
    bfrag tv;
    float s = 0.f;
#pragma unroll
    for (int j = 0; j < 8; ++j) {
      tv[j] = tile[ch * 8 + j][d];
      s += bf2f(tv[j]);
    }
    *(bfrag*)&vt[(((size_t)(b * HN + h) * 128) + d) * 1024 + n0 + ch * 8] = tv;
    s += __shfl_down(s, 4);
    s += __shfl_down(s, 2);
    s += __shfl_down(s, 1);
    if ((t & 7) == 0)
      vct[(((size_t)(b * HN + h) * 128) + d) * 16 + (n0 >> 6)] = f2bf(s * (1.0f / 64.0f));
  }
}

// ------------------------------------------------------------------
// Compressed probs (bf16 pc [b][h][n][16]) + top-8 selection bitmask.
// ------------------------------------------------------------------
__global__ __launch_bounds__(64) void cmp_sel(const short* __restrict__ qkv,
                                              const float* __restrict__ kc,
                                              short* __restrict__ pc,
                                              int* __restrict__ sel) {
  int i = blockIdx.x * 64 + threadIdx.x;  // B*H*N = 32768
  int n = i & 1023;
  int h = (i >> 10) & 15;
  int b = i >> 14;
  const short* qp = qkv + (size_t)(b * NSEQ + n) * QKV_STR + h * HDIM;
  const int nv = (n + 1) >> 6;
  float s[NBLK];
#pragma unroll
  for (int m = 0; m < NBLK; ++m) s[m] = 0.f;
  for (int d0 = 0; d0 < HDIM; d0 += 8) {
    bfrag qv = *(const bfrag*)&qp[d0];
    float qf[8];
#pragma unroll
    for (int dd = 0; dd < 8; ++dd) qf[dd] = bf2f(qv[dd]);
    for (int m = 0; m < nv; ++m) {
      const float4* kp = (const float4*)(kc + ((size_t)((b * NBLK + m) * HN + h) << 7) + d0);
      const float4 k0 = kp[0], k1 = kp[1];
      s[m] += qf[0] * k0.x + qf[1] * k0.y + qf[2] * k0.z + qf[3] * k0.w +
              qf[4] * k1.x + qf[5] * k1.y + qf[6] * k1.z + qf[7] * k1.w;
    }
  }
  float mx = -1e30f;
  for (int m = 0; m < nv; ++m) { s[m] *= SCALE; mx = fmaxf(mx, s[m]); }
  float den = 0.f;
  for (int m = 0; m < nv; ++m) { s[m] = __expf(s[m] - mx); den += s[m]; }
  const float rden = (nv > 0) ? 1.0f / den : 0.f;
  float p[NBLK];
#pragma unroll
  for (int m = 0; m < NBLK; ++m) p[m] = (m < nv) ? s[m] * rden : 0.f;
  bfrag o0, o1;
#pragma unroll
  for (int m = 0; m < 8; ++m) { o0[m] = f2bf(p[m]); o1[m] = f2bf(p[m + 8]); }
  bfrag* pout = (bfrag*)(pc + (size_t)i * 16);
  pout[0] = o0; pout[1] = o1;
  p[n >> 6] += 2.0f;
  int mask = 0;
#pragma unroll
  for (int ss = 0; ss < 8; ++ss) {
    int best = 0;
    float bv = -1e30f;
#pragma unroll
    for (int m = 0; m < NBLK; ++m)
      if (p[m] > bv) { bv = p[m]; best = m; }
    mask |= 1 << best;
    p[best] = -1e30f;
  }
  sel[i] = mask;
}

// ------------------------------------------------------------------
// MFMA attention, df-split: 2 single-wave blocks per (b,h,16-row tile),
// each computes the full score row (QK^T + exp duplicated) but only a
// 64-dim half of the PV/cmp outputs -> halved accumulators, no combine.
// XCD-swizzled grid, heavy-first. Pipelined K loads, V hoisted.
// ------------------------------------------------------------------
__global__ __launch_bounds__(64, 4) void attn_mfma(
    const short* __restrict__ qkv, const short* __restrict__ vt,
    const short* __restrict__ vct, const short* __restrict__ pc,
    const int* __restrict__ sel, short* __restrict__ o) {
  const int fid = blockIdx.x;            // 0..4095
  const int xcd = fid & 7;
  const int idx = fid >> 3;              // 0..511
  const int pair = (xcd << 2) | (idx & 3);
  const int half = (idx >> 2) & 1;       // output-d half
  const int rt = 63 - (idx >> 3);        // heavy tiles first
  const int h = pair & 15, b = pair >> 4;

  const int l = threadIdx.x;
  const int lm = l & 15, hi = l >> 4;
  const int nbase = rt * 16;
  const int dofs = half * 64;            // dim offset of this block's half

  __shared__ short p_slc[1024];
  __shared__ short p_swa[1024];

  // Q A-fragments
  const short* qrow = qkv + (size_t)(b * NSEQ + nbase + lm) * QKV_STR + h * HDIM;
  bfrag qf[4];
#pragma unroll
  for (int ks = 0; ks < 4; ++ks) qf[ks] = *(const bfrag*)&qrow[32 * ks + 8 * hi];

  // selection bits
  int selrow = sel[(size_t)(b * HN + h) * NSEQ + nbase + lm];
  int uni = selrow;
#pragma unroll
  for (int m = 1; m < 16; m <<= 1) uni |= __shfl_xor(uni, m);
  int sel4[4];
#pragma unroll
  for (int rg = 0; rg < 4; ++rg) sel4[rg] = __shfl(selrow, 4 * hi + rg);

  const int thi = nbase >> 6;
  const int tlo = (nbase >= 64) ? ((nbase - 64) >> 6) : 0;
  const int wmask = (int)((2u << thi) - (1u << tlo));
  const unsigned am = (unsigned)(uni | wmask) & (unsigned)((2u << thi) - 1);

  facc acc_slc[4] = {}, acc_swa[4] = {};
  float ps_s[4] = {0.f, 0.f, 0.f, 0.f}, ps_w[4] = {0.f, 0.f, 0.f, 0.f};

  const short* kbase0 = qkv + (size_t)(b * NSEQ) * QKV_STR + KOFS + h * HDIM + 8 * hi;
  const short* vtb0 = vt + ((size_t)(b * HN + h) * 128 + dofs) * 1024 + 8 * hi;

  int ct = __ffs((int)am) - 1;           // first active tile (am != 0 always)
  bfrag ka0, ka1, ka2, ka3;
  {
    const short* kr = kbase0 + (size_t)(ct * 64 + lm) * QKV_STR;
    ka0 = *(const bfrag*)(kr);
    ka1 = *(const bfrag*)(kr + 32);
    ka2 = *(const bfrag*)(kr + 64);
    ka3 = *(const bfrag*)(kr + 96);
  }

  while (ct >= 0) {
    const unsigned rem = am & ~((2u << ct) - 1);
    const int nct = rem ? (__ffs((int)rem) - 1) : -1;
    const bool do_s = (uni >> ct) & 1;
    const bool do_w = (wmask >> ct) & 1;

    // ---- QK^T with streaming K prefetch
    facc sacc[4] = {};
#pragma unroll
    for (int f = 0; f < 4; ++f) {
      const int pct = (f < 3) ? ct : (nct >= 0 ? nct : ct);
      const int pfr = (f < 3) ? 16 * (f + 1) : 0;
      const short* krn = kbase0 + (size_t)(pct * 64 + pfr + lm) * QKV_STR;
      bfrag kn0 = *(const bfrag*)(krn);
      bfrag kn1 = *(const bfrag*)(krn + 32);
      bfrag kn2 = *(const bfrag*)(krn + 64);
      bfrag kn3 = *(const bfrag*)(krn + 96);
      sacc[f] = MFMA16(qf[0], ka0, sacc[f]);
      sacc[f] = MFMA16(qf[1], ka1, sacc[f]);
      sacc[f] = MFMA16(qf[2], ka2, sacc[f]);
      sacc[f] = MFMA16(qf[3], ka3, sacc[f]);
      ka0 = kn0; ka1 = kn1; ka2 = kn2; ka3 = kn3;
    }

    // ---- hoist V loads (ks=0), this block's 64-dim half only
    const short* vtb = vtb0 + ct * 64;
    bfrag vb0[4];
#pragma unroll
    for (int df = 0; df < 4; ++df)
      vb0[df] = *(const bfrag*)&vtb[(size_t)(16 * df + lm) * 1024];

    // ---- exp + masks + partial sums + LDS P write (XOR-swizzled)
#pragma unroll
    for (int f = 0; f < 4; ++f) {
      const int col = ct * 64 + 16 * f + lm;
#pragma unroll
      for (int rg = 0; rg < 4; ++rg) {
        const int row = nbase + 4 * hi + rg;
        float e = __expf(sacc[f][rg] * SCALE);
        e = (col <= row) ? e : 0.f;
        float es = ((sel4[rg] >> ct) & 1) ? e : 0.f;
        float ew = (row - col <= 64) ? e : 0.f;
        ps_s[rg] += es;
        ps_w[rg] += ew;
        const int srow = 4 * hi + rg;
        const int sidx = (64 * srow + 16 * f + lm) ^ ((srow & 7) << 3);
        if (do_s) p_slc[sidx] = f2bf(es);
        if (do_w) p_swa[sidx] = f2bf(ew);
      }
    }

    // ---- PV (within-wave LDS write->read ordering; no barrier needed)
    {
      const int ridx0 = (64 * lm + 8 * hi) ^ ((lm & 7) << 3);
      bfrag pas = {}, paw = {};
      if (do_s) pas = *(const bfrag*)&p_slc[ridx0];
      if (do_w) paw = *(const bfrag*)&p_swa[ridx0];
      bfrag vb1[4];
#pragma unroll
      for (int df = 0; df < 4; ++df)
        vb1[df] = *(const bfrag*)&vtb[(size_t)(16 * df + lm) * 1024 + 32];
#pragma unroll
      for (int df = 0; df < 4; ++df) {
        if (do_s) acc_slc[df] = MFMA16(pas, vb0[df], acc_slc[df]);
        if (do_w) acc_swa[df] = MFMA16(paw, vb0[df], acc_swa[df]);
      }
      const int ridx1 = (64 * lm + 8 * hi + 32) ^ ((lm & 7) << 3);
      bfrag pas1 = {}, paw1 = {};
      if (do_s) pas1 = *(const bfrag*)&p_slc[ridx1];
      if (do_w) paw1 = *(const bfrag*)&p_swa[ridx1];
#pragma unroll
      for (int df = 0; df < 4; ++df) {
        if (do_s) acc_slc[df] = MFMA16(pas1, vb1[df], acc_slc[df]);
        if (do_w) acc_swa[df] = MFMA16(paw1, vb1[df], acc_swa[df]);
      }
    }
    ct = nct;
  }

  // ---- compressed branch: this half's 64 dims, K padded to 32
  facc acc_cmp[4] = {};
  {
    bfrag pa = {};
    if (hi < 2)
      pa = *(const bfrag*)&pc[((size_t)(b * HN + h) * NSEQ + nbase + lm) * 16 + 8 * hi];
#pragma unroll
    for (int df = 0; df < 4; ++df) {
      bfrag vb = {};
      if (hi < 2)
        vb = *(const bfrag*)&vct[(((size_t)(b * HN + h) * 128) + dofs + 16 * df + lm) * 16 + 8 * hi];
      acc_cmp[df] = MFMA16(pa, vb, acc_cmp[df]);
    }
  }

  // ---- denominators: reduce across the 16 col-lanes
#pragma unroll
  for (int m = 1; m < 16; m <<= 1) {
#pragma unroll
    for (int rg = 0; rg < 4; ++rg) {
      ps_s[rg] += __shfl_xor(ps_s[rg], m);
      ps_w[rg] += __shfl_xor(ps_w[rg], m);
    }
  }

  float inv_s[4], inv_w[4], gcv[4], gsv[4], gwv[4];
#pragma unroll
  for (int rg = 0; rg < 4; ++rg) {
    inv_s[rg] = 1.0f / ps_s[rg];
    inv_w[rg] = 1.0f / ps_w[rg];
    const short* gp = qkv + (size_t)(b * NSEQ + nbase + 4 * hi + rg) * QKV_STR + GOFS;
    gcv[rg] = 1.0f / (1.0f + __expf(-bf2f(gp[h])));
    gsv[rg] = 1.0f / (1.0f + __expf(-bf2f(gp[16 + h])));
    gwv[rg] = 1.0f / (1.0f + __expf(-bf2f(gp[32 + h])));
  }

  short* obase = o + (size_t)(b * NSEQ + nbase) * 2048 + h * HDIM + dofs;
#pragma unroll
  for (int df = 0; df < 4; ++df)
#pragma unroll
    for (int rg = 0; rg < 4; ++rg) {
      float val = gcv[rg] * acc_cmp[df][rg] +
                  gsv[rg] * acc_slc[df][rg] * inv_s[rg] +
                  gwv[rg] * acc_swa[df][rg] * inv_w[rg];
      obase[(size_t)(4 * hi + rg) * 2048 + 16 * df + lm] = f2bf(val);
    }
}

// ------------------------------------------------------------------
extern "C" void kernel_launch(void* const* d_in, const int* in_sizes, int n_in,
                              void* d_out, int out_size, void* d_ws, size_t ws_size,
                              hipStream_t stream) {
  const float* x  = (const float*)d_in[0];
  const float* Wq = (const float*)d_in[1];
  const float* Wk = (const float*)d_in[2];
  const float* Wv = (const float*)d_in[3];
  const float* Wg = (const float*)d_in[4];
  const float* Wo = (const float*)d_in[5];
  float* out = (float*)d_out;

  char* w = (char*)d_ws;
  short* x_bf = (short*)w;            // 8.4 MB (reused as o_bf)
  short* o_bf = x_bf;
  w += (size_t)2048 * 2048 * 2;
  short* w_t  = (short*)w;            // 26.2 MB (rows 6272..6399 unused pad)
  w += (size_t)6400 * 2048 * 2;
  short* qkv  = (short*)w;            // 26.2 MB (stride 6400; gate at 6144)
  w += (size_t)2048 * 6400 * 2;
  float* kc   = (float*)w; w += (size_t)65536 * 4;
  short* vct  = (short*)w; w += (size_t)65536 * 2;
  short* pcb  = (short*)w; w += (size_t)524288 * 2;
  int*   sel  = (int*)w;   w += (size_t)32768 * 4;
  short* vt   = (short*)w; w += (size_t)4194304 * 2;  // 8.4 MB
  float2* tbl = (float2*)w; w += (size_t)65536 * 8;   // 0.5 MB

  const dim3 blk(256);
  prep<<<dim3(64, 64, 6), blk, 0, stream>>>(Wq, Wk, Wv, Wg, x, w_t, x_bf, tbl);
  gemm256<<<200, dim3(512), 0, stream>>>(x_bf, w_t, qkv, 2048, 6400, 2048);
  rope_qk<<<2048, blk, 0, stream>>>(qkv, tbl);
  block_mean<<<256, blk, 0, stream>>>(qkv + KOFS, kc);
  v_transpose<<<dim3(16, 16, 2), blk, 0, stream>>>(qkv, vt, vct);
  cmp_sel<<<512, dim3(64), 0, stream>>>(qkv, kc, pcb, sel);
  transpose_cast<<<dim3(64, 64), blk, 0, stream>>>(Wo, w_t);
  attn_mfma<<<4096, dim3(64), 0, stream>>>(qkv, vt, vct, pcb, sel, o_bf);
  gemm_bf16_bt<float><<<256, blk, 0, stream>>>(o_bf, w_t, out, 2048, 2048, 2048);
}

// Round 9
// 294.185 us; speedup vs baseline: 1.5033x; 1.3992x over previous
//
#include <hip/hip_runtime.h>
#include <hip/hip_bf16.h>

// NSA forward: B=2, N=1024, D=2048, H=16, HD=128, BS=64, SEL=8, WIN=64
#define HN   16
#define HDIM 128
#define NSEQ 1024
#define NBLK 16
#define BSZ  64
#define SCALE 0.08838834764831845f
#define QKV_STR 6400   // row stride of fused qkv+gate buffer (bf16), padded to 25*256
#define KOFS 2048
#define VOFS 4096
#define GOFS 6144

typedef __attribute__((ext_vector_type(8))) short bfrag;   // 8 bf16 (4 VGPRs)
typedef __attribute__((ext_vector_type(4))) float facc;    // MFMA accumulator

__device__ __forceinline__ float bf2f(short s) {
  union { unsigned u; float f; } cv;
  cv.u = ((unsigned)(unsigned short)s) << 16;
  return cv.f;
}
__device__ __forceinline__ short f2bf(float f) {
  unsigned u = __float_as_uint(f);
  u = (u + 0x7fff + ((u >> 16) & 1)) >> 16;  // RNE
  return (short)u;
}

#define ASYNC16(gp, lp)                                                    \
  __builtin_amdgcn_global_load_lds(                                        \
      (const __attribute__((address_space(1))) void*)(gp),                 \
      (__attribute__((address_space(3))) void*)(lp), 16, 0, 0)

#define MFMA16(a, b, c) __builtin_amdgcn_mfma_f32_16x16x32_bf16(a, b, c, 0, 0, 0)

// ------------------------------------------------------------------
// prep: z=0..2 -> Wq/Wk/Wv transpose-cast into w_t rows z*2048..
//       z=3   -> Wg transposed + zero-padded to rows 6144..6271
//       z=4   -> x cast to bf16
//       z=5   -> RoPE cos/sin table
// ------------------------------------------------------------------
__global__ __launch_bounds__(256) void prep(const float* __restrict__ Wq,
                                            const float* __restrict__ Wk,
                                            const float* __restrict__ Wv,
                                            const float* __restrict__ Wg,
                                            const float* __restrict__ x,
                                            short* __restrict__ w_t,
                                            short* __restrict__ x_bf,
                                            float2* __restrict__ tbl) {
  __shared__ float tile[32][33];
  const int z = blockIdx.z;
  const int bx = blockIdx.x * 32, by = blockIdx.y * 32;
  const int tx = threadIdx.x & 31, ty = threadIdx.x >> 5;
  if (z == 5) {
    if (blockIdx.y >= 4) return;
    int i = (blockIdx.y * 64 + blockIdx.x) * 256 + threadIdx.x;  // < 65536
    int d = i & 63, n = i >> 6;
    float inv = expf(-(float)d * (9.210340371976184f / 64.0f));
    float sn, cs;
    sincosf((float)n * inv, &sn, &cs);
    tbl[i] = make_float2(cs, sn);
    return;
  }
  if (z == 4) {
#pragma unroll
    for (int i = 0; i < 4; ++i) {
      const int row = by + ty + 8 * i;
      x_bf[(size_t)row * 2048 + bx + tx] = f2bf(x[(size_t)row * 2048 + bx + tx]);
    }
    return;
  }
  if (z == 3) {
    if (blockIdx.x >= 4) return;  // only 128 dst rows
#pragma unroll
    for (int i = 0; i < 4; ++i) {
      const int c = bx + tx;
      tile[ty + 8 * i][tx] = (c < 48) ? Wg[(size_t)(by + ty + 8 * i) * 48 + c] : 0.f;
    }
    __syncthreads();
#pragma unroll
    for (int i = 0; i < 4; ++i)
      w_t[(size_t)(GOFS + bx + ty + 8 * i) * 2048 + by + tx] = f2bf(tile[tx][ty + 8 * i]);
    return;
  }
  const float* src = (z == 0) ? Wq : (z == 1) ? Wk : Wv;
#pragma unroll
  for (int i = 0; i < 4; ++i)
    tile[ty + 8 * i][tx] = src[(size_t)(by + ty + 8 * i) * 2048 + bx + tx];
  __syncthreads();
#pragma unroll
  for (int i = 0; i < 4; ++i)
    w_t[(size_t)(z * 2048 + bx + ty + 8 * i) * 2048 + by + tx] = f2bf(tile[tx][ty + 8 * i]);
}

// ------------------------------------------------------------------
// Wo transpose (reuses w_t after qkv gemm)
// ------------------------------------------------------------------
__global__ __launch_bounds__(256) void transpose_cast(const float* __restrict__ src,
                                                      short* __restrict__ dst) {
  __shared__ float tile[32][33];
  const int bx = blockIdx.x * 32, by = blockIdx.y * 32;
  const int tx = threadIdx.x & 31, ty = threadIdx.x >> 5;
#pragma unroll
  for (int i = 0; i < 4; ++i)
    tile[ty + 8 * i][tx] = src[(size_t)(by + ty + 8 * i) * 2048 + bx + tx];
  __syncthreads();
#pragma unroll
  for (int i = 0; i < 4; ++i)
    dst[(size_t)(bx + ty + 8 * i) * 2048 + by + tx] = f2bf(tile[tx][ty + 8 * i]);
}

// ------------------------------------------------------------------
// 8-phase 256x256 bf16 GEMM (T2+T3+T4+T5): C[M][N] = A[M][K]*Bt[N][K]^T
// ------------------------------------------------------------------
__global__ __launch_bounds__(512, 1) void gemm256(const short* __restrict__ A,
                                                  const short* __restrict__ Bt,
                                                  short* __restrict__ C,
                                                  int M, int N, int K) {
  __shared__ short lds[2][2][16384];  // [buf][A/B][256*64]
  const int t = threadIdx.x;
  const int l = t & 63, w = t >> 6;
  const int wm = w >> 2, wn = w & 3;
  const int lm = l & 15, hi = l >> 4;
  const int lanexor = (lm & 7) << 3;            // shorts
  const int kk0 = (hi * 8) ^ lanexor;           // ks=0 column (shorts)
  const int L = blockIdx.x;
  const int row0 = (L & 7) * 256, col0 = (L >> 3) * 256;
  const int nt = K >> 6;

  const int srow = t >> 3;
  const int scol = 8 * ((t & 7) ^ (srow & 7));
  const short* Ab = A + (size_t)(row0 + srow) * K + scol;
  const short* Bb = Bt + (size_t)(col0 + srow) * K + scol;

#define STAGE(mat, srcbase, h, tau, buf)                                     \
  {                                                                          \
    const short* g_ = (srcbase) + (size_t)(h) * 128 * K + (size_t)(tau) * 64;\
    short* d_ = &lds[buf][mat][(h) * 8192 + t * 8];                          \
    ASYNC16(g_, d_);                                                         \
    ASYNC16(g_ + (size_t)64 * K, d_ + 4096);                                 \
  }

  facc acc[8][4] = {};
  bfrag af[8], bf0[4], bf1[4];

  STAGE(0, Ab, 0, 0, 0); STAGE(0, Ab, 1, 0, 0);
  STAGE(1, Bb, 0, 0, 0); STAGE(1, Bb, 1, 0, 0);
  STAGE(1, Bb, 0, 1, 1); STAGE(1, Bb, 1, 1, 1);
  asm volatile("s_waitcnt vmcnt(4)" ::: "memory");
  __builtin_amdgcn_s_barrier();

  for (int tau = 0; tau < nt; ++tau) {
    const int c = tau & 1;
    const int tA = (tau + 1 < nt) ? tau + 1 : nt - 1;
    const int tB = (tau + 2 < nt) ? tau + 2 : nt - 1;

#define DS_A(qm)                                                             \
  _Pragma("unroll") for (int ii = 0; ii < 4; ++ii) {                         \
    const int row_ = wm * 128 + (qm) * 64 + ii * 16 + lm;                    \
    af[ii * 2 + 0] = *(const bfrag*)&lds[c][0][row_ * 64 + kk0];             \
    af[ii * 2 + 1] = *(const bfrag*)&lds[c][0][row_ * 64 + (kk0 ^ 32)];      \
  }
#define DS_B(qn, arr)                                                        \
  _Pragma("unroll") for (int jj = 0; jj < 2; ++jj) {                         \
    const int row_ = wn * 64 + (qn) * 32 + jj * 16 + lm;                     \
    arr[jj * 2 + 0] = *(const bfrag*)&lds[c][1][row_ * 64 + kk0];            \
    arr[jj * 2 + 1] = *(const bfrag*)&lds[c][1][row_ * 64 + (kk0 ^ 32)];     \
  }
#define QUAD(qm, qn, arr)                                                    \
  _Pragma("unroll") for (int ii = 0; ii < 4; ++ii)                           \
  _Pragma("unroll") for (int jj = 0; jj < 2; ++jj) {                         \
    acc[(qm)*4+ii][(qn)*2+jj] = MFMA16(af[ii*2+0], arr[jj*2+0], acc[(qm)*4+ii][(qn)*2+jj]); \
    acc[(qm)*4+ii][(qn)*2+jj] = MFMA16(af[ii*2+1], arr[jj*2+1], acc[(qm)*4+ii][(qn)*2+jj]); \
  }

    DS_A(0); DS_B(0, bf0);
    STAGE(0, Ab, 0, tA, c ^ 1);
    __builtin_amdgcn_s_barrier();
    asm volatile("s_waitcnt lgkmcnt(0)" ::: "memory");
    __builtin_amdgcn_sched_barrier(0);
    __builtin_amdgcn_s_setprio(1);
    QUAD(0, 0, bf0);
    __builtin_amdgcn_s_setprio(0);
    __builtin_amdgcn_s_barrier();

    DS_B(1, bf1);
    STAGE(0, Ab, 1, tA, c ^ 1);
    __builtin_amdgcn_s_barrier();
    asm volatile("s_waitcnt lgkmcnt(0)" ::: "memory");
    __builtin_amdgcn_sched_barrier(0);
    __builtin_amdgcn_s_setprio(1);
    QUAD(0, 1, bf1);
    __builtin_amdgcn_s_setprio(0);
    __builtin_amdgcn_s_barrier();

    DS_A(1);
    STAGE(1, Bb, 0, tB, c);
    __builtin_amdgcn_s_barrier();
    asm volatile("s_waitcnt lgkmcnt(0)" ::: "memory");
    __builtin_amdgcn_sched_barrier(0);
    __builtin_amdgcn_s_setprio(1);
    QUAD(1, 1, bf1);
    __builtin_amdgcn_s_setprio(0);
    __builtin_amdgcn_s_barrier();

    STAGE(1, Bb, 1, tB, c);
    __builtin_amdgcn_s_setprio(1);
    QUAD(1, 0, bf0);
    __builtin_amdgcn_s_setprio(0);
    asm volatile("s_waitcnt vmcnt(4)" ::: "memory");
    __builtin_amdgcn_s_barrier();
  }

#pragma unroll
  for (int i = 0; i < 8; ++i)
#pragma unroll
    for (int j = 0; j < 4; ++j)
#pragma unroll
      for (int rr = 0; rr < 4; ++rr)
        C[(size_t)(row0 + wm * 128 + i * 16 + hi * 4 + rr) * N +
          col0 + wn * 64 + j * 16 + lm] = f2bf(acc[i][j][rr]);
#undef STAGE
#undef DS_A
#undef DS_B
#undef QUAD
}

// ------------------------------------------------------------------
// bf16 MFMA GEMM (m97 128^2): C[M][N] = A[M][K] * Bt[N][K]^T (out proj)
// ------------------------------------------------------------------
__device__ __forceinline__ void store_c(float* p, float v) { *p = v; }
__device__ __forceinline__ void store_c(short* p, float v) { *p = f2bf(v); }

template <typename OT>
__global__ __launch_bounds__(256) void gemm_bf16_bt(const short* __restrict__ A,
                                                    const short* __restrict__ Bt,
                                                    OT* __restrict__ C,
                                                    int M, int N, int K) {
  __shared__ short As[128 * 32];
  __shared__ short Bs[128 * 32];
  const int t = threadIdx.x;
  const int l = t & 63, w = t >> 6;
  const int wr = w >> 1, wc = w & 1;
  const int nwg = gridDim.x;
  const int L = blockIdx.x;
  const int wg = (L & 7) * (nwg >> 3) + (L >> 3);
  const int nrow = M >> 7;
  const int row0 = (wg % nrow) * 128, col0 = (wg / nrow) * 128;
  facc acc[4][4] = {};

  const int sr = t >> 2;
  const int sk = (t & 3) * 8;
  const short* Ag0 = A + (size_t)(row0 + sr) * K + sk;
  const short* Ag1 = Ag0 + (size_t)64 * K;
  const short* Bg0 = Bt + (size_t)(col0 + sr) * K + sk;
  const short* Bg1 = Bg0 + (size_t)64 * K;
  short* la = As + t * 8;
  short* lb = Bs + t * 8;

  const int lm = l & 15;
  const int lk = (l >> 4) * 8;

  for (int k0 = 0; k0 < K; k0 += 32) {
    ASYNC16(Ag0 + k0, la);
    ASYNC16(Ag1 + k0, la + 2048);
    ASYNC16(Bg0 + k0, lb);
    ASYNC16(Bg1 + k0, lb + 2048);
    __syncthreads();
    bfrag af[4], bf[4];
#pragma unroll
    for (int i = 0; i < 4; ++i)
      af[i] = *(const bfrag*)&As[(wr * 64 + i * 16 + lm) * 32 + lk];
#pragma unroll
    for (int j = 0; j < 4; ++j)
      bf[j] = *(const bfrag*)&Bs[(wc * 64 + j * 16 + lm) * 32 + lk];
#pragma unroll
    for (int i = 0; i < 4; ++i)
#pragma unroll
      for (int j = 0; j < 4; ++j)
        acc[i][j] = MFMA16(af[i], bf[j], acc[i][j]);
    __syncthreads();
  }

  const int orow = row0 + wr * 64 + (l >> 4) * 4;
  const int ocol = col0 + wc * 64 + lm;
#pragma unroll
  for (int i = 0; i < 4; ++i)
#pragma unroll
    for (int j = 0; j < 4; ++j)
#pragma unroll
      for (int rr = 0; rr < 4; ++rr)
        store_c(&C[(size_t)(orow + i * 16 + rr) * N + ocol + j * 16], acc[i][j][rr]);
}

// ------------------------------------------------------------------
// RoPE in place on q AND k slices, table-based, 8 dims/thread
// ------------------------------------------------------------------
__global__ __launch_bounds__(256) void rope_qk(short* __restrict__ qkv,
                                               const float2* __restrict__ tbl) {
  int i = blockIdx.x * 256 + threadIdx.x;  // 524288
  int c = i & 7;
  int h = (i >> 3) & 15;
  int qk = (i >> 7) & 1;
  int n = (i >> 8) & 1023;
  int b = i >> 18;
  short* base = qkv + (size_t)(b * NSEQ + n) * QKV_STR + qk * KOFS + h * HDIM + c * 8;
  const float2* tp = tbl + n * 64 + c * 8;
  bfrag t1 = *(const bfrag*)base, t2 = *(const bfrag*)(base + 64);
  bfrag o1, o2;
#pragma unroll
  for (int j = 0; j < 8; ++j) {
    float2 cssn = tp[j];
    float a = bf2f(t1[j]), bb = bf2f(t2[j]);
    o1[j] = f2bf(a * cssn.x - bb * cssn.y);
    o2[j] = f2bf(a * cssn.y + bb * cssn.x);
  }
  *(bfrag*)base = o1;
  *(bfrag*)(base + 64) = o2;
}

// ------------------------------------------------------------------
// Block mean (roped K) -> f32 kc [b][m][h][d]
// ------------------------------------------------------------------
__global__ __launch_bounds__(256) void block_mean(const short* __restrict__ src,
                                                  float* __restrict__ dst) {
  int i = blockIdx.x * 256 + threadIdx.x;  // 65536
  int d = i & 127;
  int h = (i >> 7) & 15;
  int m = (i >> 11) & 15;
  int b = i >> 15;
  const short* p = src + (size_t)(b * NSEQ + m * BSZ) * QKV_STR + h * HDIM + d;
  float acc = 0.f;
#pragma unroll 8
  for (int j = 0; j < 64; ++j) acc += bf2f(p[(size_t)j * QKV_STR]);
  dst[i] = acc * (1.0f / 64.0f);
}

// ------------------------------------------------------------------
// V transpose -> vt[b][h][d][n], fused V block-mean -> vct[b][h][d][m]
// ------------------------------------------------------------------
__global__ __launch_bounds__(256) void v_transpose(const short* __restrict__ qkv,
                                                   short* __restrict__ vt,
                                                   short* __restrict__ vct) {
  __shared__ short tile[64][136];
  const int n0 = blockIdx.x * 64;
  const int h = blockIdx.y, b = blockIdx.z;
  const int t = threadIdx.x;
#pragma unroll
  for (int it = 0; it < 4; ++it) {
    int idx = t + 256 * it;
    int row = idx >> 4, ch = idx & 15;
    *(bfrag*)&tile[row][ch * 8] =
        *(const bfrag*)&qkv[(size_t)(b * NSEQ + n0 + row) * QKV_STR + VOFS + h * HDIM + ch * 8];
  }
  __syncthreads();
#pragma unroll
  for (int it = 0; it < 4; ++it) {
    int idx = t + 256 * it;
    int d = idx >> 3, ch = idx & 7;
    bfrag tv;
    float s = 0.f;
#pragma unroll
    for (int j = 0; j < 8; ++j) {
      tv[j] = tile[ch * 8 + j][d];
      s += bf2f(tv[j]);
    }
    *(bfrag*)&vt[(((size_t)(b * HN + h) * 128) + d) * 1024 + n0 + ch * 8] = tv;
    s += __shfl_down(s, 4);
    s += __shfl_down(s, 2);
    s += __shfl_down(s, 1);
    if ((t & 7) == 0)
      vct[(((size_t)(b * HN + h) * 128) + d) * 16 + (n0 >> 6)] = f2bf(s * (1.0f / 64.0f));
  }
}

// ------------------------------------------------------------------
// Compressed probs (bf16 pc [b][h][n][16]) + top-8 selection bitmask.
// ------------------------------------------------------------------
__global__ __launch_bounds__(64) void cmp_sel(const short* __restrict__ qkv,
                                              const float* __restrict__ kc,
                                              short* __restrict__ pc,
                                              int* __restrict__ sel) {
  int i = blockIdx.x * 64 + threadIdx.x;  // B*H*N = 32768
  int n = i & 1023;
  int h = (i >> 10) & 15;
  int b = i >> 14;
  const short* qp = qkv + (size_t)(b * NSEQ + n) * QKV_STR + h * HDIM;
  const int nv = (n + 1) >> 6;
  float s[NBLK];
#pragma unroll
  for (int m = 0; m < NBLK; ++m) s[m] = 0.f;
  for (int d0 = 0; d0 < HDIM; d0 += 8) {
    bfrag qv = *(const bfrag*)&qp[d0];
    float qf[8];
#pragma unroll
    for (int dd = 0; dd < 8; ++dd) qf[dd] = bf2f(qv[dd]);
    for (int m = 0; m < nv; ++m) {
      const float4* kp = (const float4*)(kc + ((size_t)((b * NBLK + m) * HN + h) << 7) + d0);
      const float4 k0 = kp[0], k1 = kp[1];
      s[m] += qf[0] * k0.x + qf[1] * k0.y + qf[2] * k0.z + qf[3] * k0.w +
              qf[4] * k1.x + qf[5] * k1.y + qf[6] * k1.z + qf[7] * k1.w;
    }
  }
  float mx = -1e30f;
  for (int m = 0; m < nv; ++m) { s[m] *= SCALE; mx = fmaxf(mx, s[m]); }
  float den = 0.f;
  for (int m = 0; m < nv; ++m) { s[m] = __expf(s[m] - mx); den += s[m]; }
  const float rden = (nv > 0) ? 1.0f / den : 0.f;
  float p[NBLK];
#pragma unroll
  for (int m = 0; m < NBLK; ++m) p[m] = (m < nv) ? s[m] * rden : 0.f;
  bfrag o0, o1;
#pragma unroll
  for (int m = 0; m < 8; ++m) { o0[m] = f2bf(p[m]); o1[m] = f2bf(p[m + 8]); }
  bfrag* pout = (bfrag*)(pc + (size_t)i * 16);
  pout[0] = o0; pout[1] = o1;
  p[n >> 6] += 2.0f;
  int mask = 0;
#pragma unroll
  for (int ss = 0; ss < 8; ++ss) {
    int best = 0;
    float bv = -1e30f;
#pragma unroll
    for (int m = 0; m < NBLK; ++m)
      if (p[m] > bv) { bv = p[m]; best = m; }
    mask |= 1 << best;
    p[best] = -1e30f;
  }
  sel[i] = mask;
}

// ------------------------------------------------------------------
// MFMA attention, df-split: 2 single-wave blocks per (b,h,16-row tile),
// each computes the full score row (QK^T + exp duplicated) but only a
// 64-dim half of the PV/cmp outputs -> halved accumulators, no combine.
// launch_bounds (64,2): min-waves=4 makes the allocator chase the
// 64-VGPR tier and spill (R7/R8 post-mortem) -- do not raise it.
// ------------------------------------------------------------------
__global__ __launch_bounds__(64, 2) void attn_mfma(
    const short* __restrict__ qkv, const short* __restrict__ vt,
    const short* __restrict__ vct, const short* __restrict__ pc,
    const int* __restrict__ sel, short* __restrict__ o) {
  const int fid = blockIdx.x;            // 0..4095
  const int xcd = fid & 7;
  const int idx = fid >> 3;              // 0..511
  const int pair = (xcd << 2) | (idx & 3);
  const int half = (idx >> 2) & 1;       // output-d half
  const int rt = 63 - (idx >> 3);        // heavy tiles first
  const int h = pair & 15, b = pair >> 4;

  const int l = threadIdx.x;
  const int lm = l & 15, hi = l >> 4;
  const int nbase = rt * 16;
  const int dofs = half * 64;            // dim offset of this block's half

  __shared__ short p_slc[1024];
  __shared__ short p_swa[1024];

  // Q A-fragments
  const short* qrow = qkv + (size_t)(b * NSEQ + nbase + lm) * QKV_STR + h * HDIM;
  bfrag qf[4];
#pragma unroll
  for (int ks = 0; ks < 4; ++ks) qf[ks] = *(const bfrag*)&qrow[32 * ks + 8 * hi];

  // selection bits
  int selrow = sel[(size_t)(b * HN + h) * NSEQ + nbase + lm];
  int uni = selrow;
#pragma unroll
  for (int m = 1; m < 16; m <<= 1) uni |= __shfl_xor(uni, m);
  int sel4[4];
#pragma unroll
  for (int rg = 0; rg < 4; ++rg) sel4[rg] = __shfl(selrow, 4 * hi + rg);

  const int thi = nbase >> 6;
  const int tlo = (nbase >= 64) ? ((nbase - 64) >> 6) : 0;
  const int wmask = (int)((2u << thi) - (1u << tlo));
  const unsigned am = (unsigned)(uni | wmask) & (unsigned)((2u << thi) - 1);

  facc acc_slc[4] = {}, acc_swa[4] = {};
  float ps_s[4] = {0.f, 0.f, 0.f, 0.f}, ps_w[4] = {0.f, 0.f, 0.f, 0.f};

  const short* kbase0 = qkv + (size_t)(b * NSEQ) * QKV_STR + KOFS + h * HDIM + 8 * hi;
  const short* vtb0 = vt + ((size_t)(b * HN + h) * 128 + dofs) * 1024 + 8 * hi;

  int ct = __ffs((int)am) - 1;           // first active tile (am != 0 always)
  bfrag ka0, ka1, ka2, ka3;
  {
    const short* kr = kbase0 + (size_t)(ct * 64 + lm) * QKV_STR;
    ka0 = *(const bfrag*)(kr);
    ka1 = *(const bfrag*)(kr + 32);
    ka2 = *(const bfrag*)(kr + 64);
    ka3 = *(const bfrag*)(kr + 96);
  }

  while (ct >= 0) {
    const unsigned rem = am & ~((2u << ct) - 1);
    const int nct = rem ? (__ffs((int)rem) - 1) : -1;
    const bool do_s = (uni >> ct) & 1;
    const bool do_w = (wmask >> ct) & 1;

    // ---- QK^T with streaming K prefetch
    facc sacc[4] = {};
#pragma unroll
    for (int f = 0; f < 4; ++f) {
      const int pct = (f < 3) ? ct : (nct >= 0 ? nct : ct);
      const int pfr = (f < 3) ? 16 * (f + 1) : 0;
      const short* krn = kbase0 + (size_t)(pct * 64 + pfr + lm) * QKV_STR;
      bfrag kn0 = *(const bfrag*)(krn);
      bfrag kn1 = *(const bfrag*)(krn + 32);
      bfrag kn2 = *(const bfrag*)(krn + 64);
      bfrag kn3 = *(const bfrag*)(krn + 96);
      sacc[f] = MFMA16(qf[0], ka0, sacc[f]);
      sacc[f] = MFMA16(qf[1], ka1, sacc[f]);
      sacc[f] = MFMA16(qf[2], ka2, sacc[f]);
      sacc[f] = MFMA16(qf[3], ka3, sacc[f]);
      ka0 = kn0; ka1 = kn1; ka2 = kn2; ka3 = kn3;
    }

    // ---- hoist V loads (ks=0), this block's 64-dim half only
    const short* vtb = vtb0 + ct * 64;
    bfrag vb0[4];
#pragma unroll
    for (int df = 0; df < 4; ++df)
      vb0[df] = *(const bfrag*)&vtb[(size_t)(16 * df + lm) * 1024];

    // ---- exp + masks + partial sums + LDS P write (XOR-swizzled)
#pragma unroll
    for (int f = 0; f < 4; ++f) {
      const int col = ct * 64 + 16 * f + lm;
#pragma unroll
      for (int rg = 0; rg < 4; ++rg) {
        const int row = nbase + 4 * hi + rg;
        float e = __expf(sacc[f][rg] * SCALE);
        e = (col <= row) ? e : 0.f;
        float es = ((sel4[rg] >> ct) & 1) ? e : 0.f;
        float ew = (row - col <= 64) ? e : 0.f;
        ps_s[rg] += es;
        ps_w[rg] += ew;
        const int srow = 4 * hi + rg;
        const int sidx = (64 * srow + 16 * f + lm) ^ ((srow & 7) << 3);
        if (do_s) p_slc[sidx] = f2bf(es);
        if (do_w) p_swa[sidx] = f2bf(ew);
      }
    }

    // ---- PV (within-wave LDS write->read ordering; no barrier needed)
    {
      const int ridx0 = (64 * lm + 8 * hi) ^ ((lm & 7) << 3);
      bfrag pas = {}, paw = {};
      if (do_s) pas = *(const bfrag*)&p_slc[ridx0];
      if (do_w) paw = *(const bfrag*)&p_swa[ridx0];
      bfrag vb1[4];
#pragma unroll
      for (int df = 0; df < 4; ++df)
        vb1[df] = *(const bfrag*)&vtb[(size_t)(16 * df + lm) * 1024 + 32];
#pragma unroll
      for (int df = 0; df < 4; ++df) {
        if (do_s) acc_slc[df] = MFMA16(pas, vb0[df], acc_slc[df]);
        if (do_w) acc_swa[df] = MFMA16(paw, vb0[df], acc_swa[df]);
      }
      const int ridx1 = (64 * lm + 8 * hi + 32) ^ ((lm & 7) << 3);
      bfrag pas1 = {}, paw1 = {};
      if (do_s) pas1 = *(const bfrag*)&p_slc[ridx1];
      if (do_w) paw1 = *(const bfrag*)&p_swa[ridx1];
#pragma unroll
      for (int df = 0; df < 4; ++df) {
        if (do_s) acc_slc[df] = MFMA16(pas1, vb1[df], acc_slc[df]);
        if (do_w) acc_swa[df] = MFMA16(paw1, vb1[df], acc_swa[df]);
      }
    }
    ct = nct;
  }

  // ---- compressed branch: this half's 64 dims, K padded to 32
  facc acc_cmp[4] = {};
  {
    bfrag pa = {};
    if (hi < 2)
      pa = *(const bfrag*)&pc[((size_t)(b * HN + h) * NSEQ + nbase + lm) * 16 + 8 * hi];
#pragma unroll
    for (int df = 0; df < 4; ++df) {
      bfrag vb = {};
      if (hi < 2)
        vb = *(const bfrag*)&vct[(((size_t)(b * HN + h) * 128) + dofs + 16 * df + lm) * 16 + 8 * hi];
      acc_cmp[df] = MFMA16(pa, vb, acc_cmp[df]);
    }
  }

  // ---- denominators: reduce across the 16 col-lanes
#pragma unroll
  for (int m = 1; m < 16; m <<= 1) {
#pragma unroll
    for (int rg = 0; rg < 4; ++rg) {
      ps_s[rg] += __shfl_xor(ps_s[rg], m);
      ps_w[rg] += __shfl_xor(ps_w[rg], m);
    }
  }

  float inv_s[4], inv_w[4], gcv[4], gsv[4], gwv[4];
#pragma unroll
  for (int rg = 0; rg < 4; ++rg) {
    inv_s[rg] = 1.0f / ps_s[rg];
    inv_w[rg] = 1.0f / ps_w[rg];
    const short* gp = qkv + (size_t)(b * NSEQ + nbase + 4 * hi + rg) * QKV_STR + GOFS;
    gcv[rg] = 1.0f / (1.0f + __expf(-bf2f(gp[h])));
    gsv[rg] = 1.0f / (1.0f + __expf(-bf2f(gp[16 + h])));
    gwv[rg] = 1.0f / (1.0f + __expf(-bf2f(gp[32 + h])));
  }

  short* obase = o + (size_t)(b * NSEQ + nbase) * 2048 + h * HDIM + dofs;
#pragma unroll
  for (int df = 0; df < 4; ++df)
#pragma unroll
    for (int rg = 0; rg < 4; ++rg) {
      float val = gcv[rg] * acc_cmp[df][rg] +
                  gsv[rg] * acc_slc[df][rg] * inv_s[rg] +
                  gwv[rg] * acc_swa[df][rg] * inv_w[rg];
      obase[(size_t)(4 * hi + rg) * 2048 + 16 * df + lm] = f2bf(val);
    }
}

// ------------------------------------------------------------------
extern "C" void kernel_launch(void* const* d_in, const int* in_sizes, int n_in,
                              void* d_out, int out_size, void* d_ws, size_t ws_size,
                              hipStream_t stream) {
  const float* x  = (const float*)d_in[0];
  const float* Wq = (const float*)d_in[1];
  const float* Wk = (const float*)d_in[2];
  const float* Wv = (const float*)d_in[3];
  const float* Wg = (const float*)d_in[4];
  const float* Wo = (const float*)d_in[5];
  float* out = (float*)d_out;

  char* w = (char*)d_ws;
  short* x_bf = (short*)w;            // 8.4 MB (reused as o_bf)
  short* o_bf = x_bf;
  w += (size_t)2048 * 2048 * 2;
  short* w_t  = (short*)w;            // 26.2 MB (rows 6272..6399 unused pad)
  w += (size_t)6400 * 2048 * 2;
  short* qkv  = (short*)w;            // 26.2 MB (stride 6400; gate at 6144)
  w += (size_t)2048 * 6400 * 2;
  float* kc   = (float*)w; w += (size_t)65536 * 4;
  short* vct  = (short*)w; w += (size_t)65536 * 2;
  short* pcb  = (short*)w; w += (size_t)524288 * 2;
  int*   sel  = (int*)w;   w += (size_t)32768 * 4;
  short* vt   = (short*)w; w += (size_t)4194304 * 2;  // 8.4 MB
  float2* tbl = (float2*)w; w += (size_t)65536 * 8;   // 0.5 MB

  const dim3 blk(256);
  prep<<<dim3(64, 64, 6), blk, 0, stream>>>(Wq, Wk, Wv, Wg, x, w_t, x_bf, tbl);
  gemm256<<<200, dim3(512), 0, stream>>>(x_bf, w_t, qkv, 2048, 6400, 2048);
  rope_qk<<<2048, blk, 0, stream>>>(qkv, tbl);
  block_mean<<<256, blk, 0, stream>>>(qkv + KOFS, kc);
  v_transpose<<<dim3(16, 16, 2), blk, 0, stream>>>(qkv, vt, vct);
  cmp_sel<<<512, dim3(64), 0, stream>>>(qkv, kc, pcb, sel);
  transpose_cast<<<dim3(64, 64), blk, 0, stream>>>(Wo, w_t);
  attn_mfma<<<4096, dim3(64), 0, stream>>>(qkv, vt, vct, pcb, sel, o_bf);
  gemm_bf16_bt<float><<<256, blk, 0, stream>>>(o_bf, w_t, out, 2048, 2048, 2048);
}

// Round 10
// 265.050 us; speedup vs baseline: 1.6686x; 1.1099x over previous
//
#include <hip/hip_runtime.h>
#include <hip/hip_bf16.h>

// NSA forward: B=2, N=1024, D=2048, H=16, HD=128, BS=64, SEL=8, WIN=64
#define HN   16
#define HDIM 128
#define NSEQ 1024
#define NBLK 16
#define BSZ  64
#define SCALE 0.08838834764831845f
#define QKV_STR 6400   // row stride of fused qkv+gate buffer (bf16), padded to 25*256
#define KOFS 2048
#define VOFS 4096
#define GOFS 6144

typedef __attribute__((ext_vector_type(8))) short bfrag;   // 8 bf16 (4 VGPRs)
typedef __attribute__((ext_vector_type(4))) float facc;    // MFMA accumulator

__device__ __forceinline__ float bf2f(short s) {
  union { unsigned u; float f; } cv;
  cv.u = ((unsigned)(unsigned short)s) << 16;
  return cv.f;
}
__device__ __forceinline__ short f2bf(float f) {
  unsigned u = __float_as_uint(f);
  u = (u + 0x7fff + ((u >> 16) & 1)) >> 16;  // RNE
  return (short)u;
}

#define ASYNC16(gp, lp)                                                    \
  __builtin_amdgcn_global_load_lds(                                        \
      (const __attribute__((address_space(1))) void*)(gp),                 \
      (__attribute__((address_space(3))) void*)(lp), 16, 0, 0)

#define MFMA16(a, b, c) __builtin_amdgcn_mfma_f32_16x16x32_bf16(a, b, c, 0, 0, 0)

// ------------------------------------------------------------------
// prep: z=0..2 -> Wq/Wk/Wv transpose-cast into w_t rows z*2048..
//       z=3   -> Wg transposed + zero-padded to rows 6144..6271
//       z=4   -> x cast to bf16
//       z=5   -> RoPE cos/sin table
// ------------------------------------------------------------------
__global__ __launch_bounds__(256) void prep(const float* __restrict__ Wq,
                                            const float* __restrict__ Wk,
                                            const float* __restrict__ Wv,
                                            const float* __restrict__ Wg,
                                            const float* __restrict__ x,
                                            short* __restrict__ w_t,
                                            short* __restrict__ x_bf,
                                            float2* __restrict__ tbl) {
  __shared__ float tile[32][33];
  const int z = blockIdx.z;
  const int bx = blockIdx.x * 32, by = blockIdx.y * 32;
  const int tx = threadIdx.x & 31, ty = threadIdx.x >> 5;
  if (z == 5) {
    if (blockIdx.y >= 4) return;
    int i = (blockIdx.y * 64 + blockIdx.x) * 256 + threadIdx.x;  // < 65536
    int d = i & 63, n = i >> 6;
    float inv = expf(-(float)d * (9.210340371976184f / 64.0f));
    float sn, cs;
    sincosf((float)n * inv, &sn, &cs);
    tbl[i] = make_float2(cs, sn);
    return;
  }
  if (z == 4) {
#pragma unroll
    for (int i = 0; i < 4; ++i) {
      const int row = by + ty + 8 * i;
      x_bf[(size_t)row * 2048 + bx + tx] = f2bf(x[(size_t)row * 2048 + bx + tx]);
    }
    return;
  }
  if (z == 3) {
    if (blockIdx.x >= 4) return;  // only 128 dst rows
#pragma unroll
    for (int i = 0; i < 4; ++i) {
      const int c = bx + tx;
      tile[ty + 8 * i][tx] = (c < 48) ? Wg[(size_t)(by + ty + 8 * i) * 48 + c] : 0.f;
    }
    __syncthreads();
#pragma unroll
    for (int i = 0; i < 4; ++i)
      w_t[(size_t)(GOFS + bx + ty + 8 * i) * 2048 + by + tx] = f2bf(tile[tx][ty + 8 * i]);
    return;
  }
  const float* src = (z == 0) ? Wq : (z == 1) ? Wk : Wv;
#pragma unroll
  for (int i = 0; i < 4; ++i)
    tile[ty + 8 * i][tx] = src[(size_t)(by + ty + 8 * i) * 2048 + bx + tx];
  __syncthreads();
#pragma unroll
  for (int i = 0; i < 4; ++i)
    w_t[(size_t)(z * 2048 + bx + ty + 8 * i) * 2048 + by + tx] = f2bf(tile[tx][ty + 8 * i]);
}

// ------------------------------------------------------------------
// Wo transpose (reuses w_t after qkv gemm)
// ------------------------------------------------------------------
__global__ __launch_bounds__(256) void transpose_cast(const float* __restrict__ src,
                                                      short* __restrict__ dst) {
  __shared__ float tile[32][33];
  const int bx = blockIdx.x * 32, by = blockIdx.y * 32;
  const int tx = threadIdx.x & 31, ty = threadIdx.x >> 5;
#pragma unroll
  for (int i = 0; i < 4; ++i)
    tile[ty + 8 * i][tx] = src[(size_t)(by + ty + 8 * i) * 2048 + bx + tx];
  __syncthreads();
#pragma unroll
  for (int i = 0; i < 4; ++i)
    dst[(size_t)(bx + ty + 8 * i) * 2048 + by + tx] = f2bf(tile[tx][ty + 8 * i]);
}

// ------------------------------------------------------------------
// 8-phase 256x256 bf16 GEMM (T2+T3+T4+T5): C[M][N] = A[M][K]*Bt[N][K]^T
// ------------------------------------------------------------------
__global__ __launch_bounds__(512, 1) void gemm256(const short* __restrict__ A,
                                                  const short* __restrict__ Bt,
                                                  short* __restrict__ C,
                                                  int M, int N, int K) {
  __shared__ short lds[2][2][16384];  // [buf][A/B][256*64]
  const int t = threadIdx.x;
  const int l = t & 63, w = t >> 6;
  const int wm = w >> 2, wn = w & 3;
  const int lm = l & 15, hi = l >> 4;
  const int lanexor = (lm & 7) << 3;            // shorts
  const int kk0 = (hi * 8) ^ lanexor;           // ks=0 column (shorts)
  const int L = blockIdx.x;
  const int row0 = (L & 7) * 256, col0 = (L >> 3) * 256;
  const int nt = K >> 6;

  const int srow = t >> 3;
  const int scol = 8 * ((t & 7) ^ (srow & 7));
  const short* Ab = A + (size_t)(row0 + srow) * K + scol;
  const short* Bb = Bt + (size_t)(col0 + srow) * K + scol;

#define STAGE(mat, srcbase, h, tau, buf)                                     \
  {                                                                          \
    const short* g_ = (srcbase) + (size_t)(h) * 128 * K + (size_t)(tau) * 64;\
    short* d_ = &lds[buf][mat][(h) * 8192 + t * 8];                          \
    ASYNC16(g_, d_);                                                         \
    ASYNC16(g_ + (size_t)64 * K, d_ + 4096);                                 \
  }

  facc acc[8][4] = {};
  bfrag af[8], bf0[4], bf1[4];

  STAGE(0, Ab, 0, 0, 0); STAGE(0, Ab, 1, 0, 0);
  STAGE(1, Bb, 0, 0, 0); STAGE(1, Bb, 1, 0, 0);
  STAGE(1, Bb, 0, 1, 1); STAGE(1, Bb, 1, 1, 1);
  asm volatile("s_waitcnt vmcnt(4)" ::: "memory");
  __builtin_amdgcn_s_barrier();

  for (int tau = 0; tau < nt; ++tau) {
    const int c = tau & 1;
    const int tA = (tau + 1 < nt) ? tau + 1 : nt - 1;
    const int tB = (tau + 2 < nt) ? tau + 2 : nt - 1;

#define DS_A(qm)                                                             \
  _Pragma("unroll") for (int ii = 0; ii < 4; ++ii) {                         \
    const int row_ = wm * 128 + (qm) * 64 + ii * 16 + lm;                    \
    af[ii * 2 + 0] = *(const bfrag*)&lds[c][0][row_ * 64 + kk0];             \
    af[ii * 2 + 1] = *(const bfrag*)&lds[c][0][row_ * 64 + (kk0 ^ 32)];      \
  }
#define DS_B(qn, arr)                                                        \
  _Pragma("unroll") for (int jj = 0; jj < 2; ++jj) {                         \
    const int row_ = wn * 64 + (qn) * 32 + jj * 16 + lm;                     \
    arr[jj * 2 + 0] = *(const bfrag*)&lds[c][1][row_ * 64 + kk0];            \
    arr[jj * 2 + 1] = *(const bfrag*)&lds[c][1][row_ * 64 + (kk0 ^ 32)];     \
  }
#define QUAD(qm, qn, arr)                                                    \
  _Pragma("unroll") for (int ii = 0; ii < 4; ++ii)                           \
  _Pragma("unroll") for (int jj = 0; jj < 2; ++jj) {                         \
    acc[(qm)*4+ii][(qn)*2+jj] = MFMA16(af[ii*2+0], arr[jj*2+0], acc[(qm)*4+ii][(qn)*2+jj]); \
    acc[(qm)*4+ii][(qn)*2+jj] = MFMA16(af[ii*2+1], arr[jj*2+1], acc[(qm)*4+ii][(qn)*2+jj]); \
  }

    DS_A(0); DS_B(0, bf0);
    STAGE(0, Ab, 0, tA, c ^ 1);
    __builtin_amdgcn_s_barrier();
    asm volatile("s_waitcnt lgkmcnt(0)" ::: "memory");
    __builtin_amdgcn_sched_barrier(0);
    __builtin_amdgcn_s_setprio(1);
    QUAD(0, 0, bf0);
    __builtin_amdgcn_s_setprio(0);
    __builtin_amdgcn_s_barrier();

    DS_B(1, bf1);
    STAGE(0, Ab, 1, tA, c ^ 1);
    __builtin_amdgcn_s_barrier();
    asm volatile("s_waitcnt lgkmcnt(0)" ::: "memory");
    __builtin_amdgcn_sched_barrier(0);
    __builtin_amdgcn_s_setprio(1);
    QUAD(0, 1, bf1);
    __builtin_amdgcn_s_setprio(0);
    __builtin_amdgcn_s_barrier();

    DS_A(1);
    STAGE(1, Bb, 0, tB, c);
    __builtin_amdgcn_s_barrier();
    asm volatile("s_waitcnt lgkmcnt(0)" ::: "memory");
    __builtin_amdgcn_sched_barrier(0);
    __builtin_amdgcn_s_setprio(1);
    QUAD(1, 1, bf1);
    __builtin_amdgcn_s_setprio(0);
    __builtin_amdgcn_s_barrier();

    STAGE(1, Bb, 1, tB, c);
    __builtin_amdgcn_s_setprio(1);
    QUAD(1, 0, bf0);
    __builtin_amdgcn_s_setprio(0);
    asm volatile("s_waitcnt vmcnt(4)" ::: "memory");
    __builtin_amdgcn_s_barrier();
  }

#pragma unroll
  for (int i = 0; i < 8; ++i)
#pragma unroll
    for (int j = 0; j < 4; ++j)
#pragma unroll
      for (int rr = 0; rr < 4; ++rr)
        C[(size_t)(row0 + wm * 128 + i * 16 + hi * 4 + rr) * N +
          col0 + wn * 64 + j * 16 + lm] = f2bf(acc[i][j][rr]);
#undef STAGE
#undef DS_A
#undef DS_B
#undef QUAD
}

// ------------------------------------------------------------------
// bf16 MFMA GEMM (m97 128^2): C[M][N] = A[M][K] * Bt[N][K]^T (out proj)
// ------------------------------------------------------------------
__device__ __forceinline__ void store_c(float* p, float v) { *p = v; }
__device__ __forceinline__ void store_c(short* p, float v) { *p = f2bf(v); }

template <typename OT>
__global__ __launch_bounds__(256) void gemm_bf16_bt(const short* __restrict__ A,
                                                    const short* __restrict__ Bt,
                                                    OT* __restrict__ C,
                                                    int M, int N, int K) {
  __shared__ short As[128 * 32];
  __shared__ short Bs[128 * 32];
  const int t = threadIdx.x;
  const int l = t & 63, w = t >> 6;
  const int wr = w >> 1, wc = w & 1;
  const int nwg = gridDim.x;
  const int L = blockIdx.x;
  const int wg = (L & 7) * (nwg >> 3) + (L >> 3);
  const int nrow = M >> 7;
  const int row0 = (wg % nrow) * 128, col0 = (wg / nrow) * 128;
  facc acc[4][4] = {};

  const int sr = t >> 2;
  const int sk = (t & 3) * 8;
  const short* Ag0 = A + (size_t)(row0 + sr) * K + sk;
  const short* Ag1 = Ag0 + (size_t)64 * K;
  const short* Bg0 = Bt + (size_t)(col0 + sr) * K + sk;
  const short* Bg1 = Bg0 + (size_t)64 * K;
  short* la = As + t * 8;
  short* lb = Bs + t * 8;

  const int lm = l & 15;
  const int lk = (l >> 4) * 8;

  for (int k0 = 0; k0 < K; k0 += 32) {
    ASYNC16(Ag0 + k0, la);
    ASYNC16(Ag1 + k0, la + 2048);
    ASYNC16(Bg0 + k0, lb);
    ASYNC16(Bg1 + k0, lb + 2048);
    __syncthreads();
    bfrag af[4], bf[4];
#pragma unroll
    for (int i = 0; i < 4; ++i)
      af[i] = *(const bfrag*)&As[(wr * 64 + i * 16 + lm) * 32 + lk];
#pragma unroll
    for (int j = 0; j < 4; ++j)
      bf[j] = *(const bfrag*)&Bs[(wc * 64 + j * 16 + lm) * 32 + lk];
#pragma unroll
    for (int i = 0; i < 4; ++i)
#pragma unroll
      for (int j = 0; j < 4; ++j)
        acc[i][j] = MFMA16(af[i], bf[j], acc[i][j]);
    __syncthreads();
  }

  const int orow = row0 + wr * 64 + (l >> 4) * 4;
  const int ocol = col0 + wc * 64 + lm;
#pragma unroll
  for (int i = 0; i < 4; ++i)
#pragma unroll
    for (int j = 0; j < 4; ++j)
#pragma unroll
      for (int rr = 0; rr < 4; ++rr)
        store_c(&C[(size_t)(orow + i * 16 + rr) * N + ocol + j * 16], acc[i][j][rr]);
}

// ------------------------------------------------------------------
// RoPE in place on q AND k slices, table-based, 8 dims/thread
// ------------------------------------------------------------------
__global__ __launch_bounds__(256) void rope_qk(short* __restrict__ qkv,
                                               const float2* __restrict__ tbl) {
  int i = blockIdx.x * 256 + threadIdx.x;  // 524288
  int c = i & 7;
  int h = (i >> 3) & 15;
  int qk = (i >> 7) & 1;
  int n = (i >> 8) & 1023;
  int b = i >> 18;
  short* base = qkv + (size_t)(b * NSEQ + n) * QKV_STR + qk * KOFS + h * HDIM + c * 8;
  const float2* tp = tbl + n * 64 + c * 8;
  bfrag t1 = *(const bfrag*)base, t2 = *(const bfrag*)(base + 64);
  bfrag o1, o2;
#pragma unroll
  for (int j = 0; j < 8; ++j) {
    float2 cssn = tp[j];
    float a = bf2f(t1[j]), bb = bf2f(t2[j]);
    o1[j] = f2bf(a * cssn.x - bb * cssn.y);
    o2[j] = f2bf(a * cssn.y + bb * cssn.x);
  }
  *(bfrag*)base = o1;
  *(bfrag*)(base + 64) = o2;
}

// ------------------------------------------------------------------
// Block mean (roped K) -> f32 kc [b][m][h][d]
// ------------------------------------------------------------------
__global__ __launch_bounds__(256) void block_mean(const short* __restrict__ src,
                                                  float* __restrict__ dst) {
  int i = blockIdx.x * 256 + threadIdx.x;  // 65536
  int d = i & 127;
  int h = (i >> 7) & 15;
  int m = (i >> 11) & 15;
  int b = i >> 15;
  const short* p = src + (size_t)(b * NSEQ + m * BSZ) * QKV_STR + h * HDIM + d;
  float acc = 0.f;
#pragma unroll 8
  for (int j = 0; j < 64; ++j) acc += bf2f(p[(size_t)j * QKV_STR]);
  dst[i] = acc * (1.0f / 64.0f);
}

// ------------------------------------------------------------------
// V transpose -> vt[b][h][d][n], fused V block-mean -> vct[b][h][d][m]
// ------------------------------------------------------------------
__global__ __launch_bounds__(256) void v_transpose(const short* __restrict__ qkv,
                                                   short* __restrict__ vt,
                                                   short* __restrict__ vct) {
  __shared__ short tile[64][136];
  const int n0 = blockIdx.x * 64;
  const int h = blockIdx.y, b = blockIdx.z;
  const int t = threadIdx.x;
#pragma unroll
  for (int it = 0; it < 4; ++it) {
    int idx = t + 256 * it;
    int row = idx >> 4, ch = idx & 15;
    *(bfrag*)&tile[row][ch * 8] =
        *(const bfrag*)&qkv[(size_t)(b * NSEQ + n0 + row) * QKV_STR + VOFS + h * HDIM + ch * 8];
  }
  __syncthreads();
#pragma unroll
  for (int it = 0; it < 4; ++it) {
    int idx = t + 256 * it;
    int d = idx >> 3, ch = idx & 7;
    bfrag tv;
    float s = 0.f;
#pragma unroll
    for (int j = 0; j < 8; ++j) {
      tv[j] = tile[ch * 8 + j][d];
      s += bf2f(tv[j]);
    }
    *(bfrag*)&vt[(((size_t)(b * HN + h) * 128) + d) * 1024 + n0 + ch * 8] = tv;
    s += __shfl_down(s, 4);
    s += __shfl_down(s, 2);
    s += __shfl_down(s, 1);
    if ((t & 7) == 0)
      vct[(((size_t)(b * HN + h) * 128) + d) * 16 + (n0 >> 6)] = f2bf(s * (1.0f / 64.0f));
  }
}

// ------------------------------------------------------------------
// Compressed probs (bf16 pc [b][h][n][16]) + top-8 selection bitmask.
// ------------------------------------------------------------------
__global__ __launch_bounds__(64) void cmp_sel(const short* __restrict__ qkv,
                                              const float* __restrict__ kc,
                                              short* __restrict__ pc,
                                              int* __restrict__ sel) {
  int i = blockIdx.x * 64 + threadIdx.x;  // B*H*N = 32768
  int n = i & 1023;
  int h = (i >> 10) & 15;
  int b = i >> 14;
  const short* qp = qkv + (size_t)(b * NSEQ + n) * QKV_STR + h * HDIM;
  const int nv = (n + 1) >> 6;
  float s[NBLK];
#pragma unroll
  for (int m = 0; m < NBLK; ++m) s[m] = 0.f;
  for (int d0 = 0; d0 < HDIM; d0 += 8) {
    bfrag qv = *(const bfrag*)&qp[d0];
    float qf[8];
#pragma unroll
    for (int dd = 0; dd < 8; ++dd) qf[dd] = bf2f(qv[dd]);
    for (int m = 0; m < nv; ++m) {
      const float4* kp = (const float4*)(kc + ((size_t)((b * NBLK + m) * HN + h) << 7) + d0);
      const float4 k0 = kp[0], k1 = kp[1];
      s[m] += qf[0] * k0.x + qf[1] * k0.y + qf[2] * k0.z + qf[3] * k0.w +
              qf[4] * k1.x + qf[5] * k1.y + qf[6] * k1.z + qf[7] * k1.w;
    }
  }
  float mx = -1e30f;
  for (int m = 0; m < nv; ++m) { s[m] *= SCALE; mx = fmaxf(mx, s[m]); }
  float den = 0.f;
  for (int m = 0; m < nv; ++m) { s[m] = __expf(s[m] - mx); den += s[m]; }
  const float rden = (nv > 0) ? 1.0f / den : 0.f;
  float p[NBLK];
#pragma unroll
  for (int m = 0; m < NBLK; ++m) p[m] = (m < nv) ? s[m] * rden : 0.f;
  bfrag o0, o1;
#pragma unroll
  for (int m = 0; m < 8; ++m) { o0[m] = f2bf(p[m]); o1[m] = f2bf(p[m + 8]); }
  bfrag* pout = (bfrag*)(pc + (size_t)i * 16);
  pout[0] = o0; pout[1] = o1;
  p[n >> 6] += 2.0f;
  int mask = 0;
#pragma unroll
  for (int ss = 0; ss < 8; ++ss) {
    int best = 0;
    float bv = -1e30f;
#pragma unroll
    for (int m = 0; m < NBLK; ++m)
      if (p[m] > bv) { bv = p[m]; best = m; }
    mask |= 1 << best;
    p[best] = -1e30f;
  }
  sel[i] = mask;
}

// ------------------------------------------------------------------
// MFMA attention. 2 waves per (b,h,16-row tile): active tiles split
// odd/even between waves (disjoint partial sums, NO duplicated QK^T),
// combined via LDS at the end. launch_bounds (128,2): min-waves=4
// forces the 64-VGPR tier and spills (R7/R8 lesson) -- keep at 2.
// ------------------------------------------------------------------
__global__ __launch_bounds__(128, 2) void attn_mfma(
    const short* __restrict__ qkv, const short* __restrict__ vt,
    const short* __restrict__ vct, const short* __restrict__ pc,
    const int* __restrict__ sel, short* __restrict__ o) {
  const int fid = blockIdx.x;            // 0..2047
  const int xcd = fid & 7;
  const int idx = fid >> 3;              // 0..255
  const int pair = (xcd << 2) | (idx & 3);
  const int rt = 63 - (idx >> 2);        // heavy tiles first
  const int h = pair & 15, b = pair >> 4;

  const int tid = threadIdx.x;
  const int wid = tid >> 6;
  const int l = tid & 63;
  const int lm = l & 15, hi = l >> 4;
  const int nbase = rt * 16;

  __shared__ short pbuf[2][2][1024];     // [wid][slc/swa][...]  (8 KB)
  float* cb = (float*)&pbuf[0][0][0];    // combine overlay, 2048 floats

  // Q A-fragments
  const short* qrow = qkv + (size_t)(b * NSEQ + nbase + lm) * QKV_STR + h * HDIM;
  bfrag qf[4];
#pragma unroll
  for (int ks = 0; ks < 4; ++ks) qf[ks] = *(const bfrag*)&qrow[32 * ks + 8 * hi];

  // selection bits
  int selrow = sel[(size_t)(b * HN + h) * NSEQ + nbase + lm];
  int uni = selrow;
#pragma unroll
  for (int m = 1; m < 16; m <<= 1) uni |= __shfl_xor(uni, m);
  int sel4[4];
#pragma unroll
  for (int rg = 0; rg < 4; ++rg) sel4[rg] = __shfl(selrow, 4 * hi + rg);

  const int thi = nbase >> 6;
  const int tlo = (nbase >= 64) ? ((nbase - 64) >> 6) : 0;
  const int wmask = (int)((2u << thi) - (1u << tlo));
  const unsigned am = (unsigned)(uni | wmask) & (unsigned)((2u << thi) - 1);

  // split active tiles alternately between the 2 waves
  unsigned amw = 0;
  {
    unsigned mm = am;
    int p = 0;
    while (mm) {
      unsigned lb = mm & (0u - mm);
      if ((p & 1) == wid) amw |= lb;
      mm ^= lb;
      ++p;
    }
  }

  facc acc_slc[8] = {}, acc_swa[8] = {};
  float ps_s[4] = {0.f, 0.f, 0.f, 0.f}, ps_w[4] = {0.f, 0.f, 0.f, 0.f};

  const short* kbase0 = qkv + (size_t)(b * NSEQ) * QKV_STR + KOFS + h * HDIM + 8 * hi;
  const short* vtb0 = vt + ((size_t)(b * HN + h) * 128) * 1024 + 8 * hi;
  short* p_slc = &pbuf[wid][0][0];
  short* p_swa = &pbuf[wid][1][0];

  int ct = -1;
  bfrag ka0, ka1, ka2, ka3;
  if (amw) {
    ct = __ffs((int)amw) - 1;
    const short* kr = kbase0 + (size_t)(ct * 64 + lm) * QKV_STR;
    ka0 = *(const bfrag*)(kr);
    ka1 = *(const bfrag*)(kr + 32);
    ka2 = *(const bfrag*)(kr + 64);
    ka3 = *(const bfrag*)(kr + 96);
  }

  while (ct >= 0) {
    const unsigned rem = amw & ~((2u << ct) - 1);
    const int nct = rem ? (__ffs((int)rem) - 1) : -1;
    const bool do_s = (uni >> ct) & 1;
    const bool do_w = (wmask >> ct) & 1;

    // ---- QK^T with streaming K prefetch
    facc sacc[4] = {};
#pragma unroll
    for (int f = 0; f < 4; ++f) {
      const int pct = (f < 3) ? ct : (nct >= 0 ? nct : ct);
      const int pfr = (f < 3) ? 16 * (f + 1) : 0;
      const short* krn = kbase0 + (size_t)(pct * 64 + pfr + lm) * QKV_STR;
      bfrag kn0 = *(const bfrag*)(krn);
      bfrag kn1 = *(const bfrag*)(krn + 32);
      bfrag kn2 = *(const bfrag*)(krn + 64);
      bfrag kn3 = *(const bfrag*)(krn + 96);
      sacc[f] = MFMA16(qf[0], ka0, sacc[f]);
      sacc[f] = MFMA16(qf[1], ka1, sacc[f]);
      sacc[f] = MFMA16(qf[2], ka2, sacc[f]);
      sacc[f] = MFMA16(qf[3], ka3, sacc[f]);
      ka0 = kn0; ka1 = kn1; ka2 = kn2; ka3 = kn3;
    }

    // ---- hoist V loads (ks=0)
    const short* vtb = vtb0 + ct * 64;
    bfrag vb0[8];
#pragma unroll
    for (int df = 0; df < 8; ++df)
      vb0[df] = *(const bfrag*)&vtb[(size_t)(16 * df + lm) * 1024];

    // ---- exp + masks + partial sums + LDS P write (XOR-swizzled)
#pragma unroll
    for (int f = 0; f < 4; ++f) {
      const int col = ct * 64 + 16 * f + lm;
#pragma unroll
      for (int rg = 0; rg < 4; ++rg) {
        const int row = nbase + 4 * hi + rg;
        float e = __expf(sacc[f][rg] * SCALE);
        e = (col <= row) ? e : 0.f;
        float es = ((sel4[rg] >> ct) & 1) ? e : 0.f;
        float ew = (row - col <= 64) ? e : 0.f;
        ps_s[rg] += es;
        ps_w[rg] += ew;
        const int srow = 4 * hi + rg;
        const int sidx = (64 * srow + 16 * f + lm) ^ ((srow & 7) << 3);
        if (do_s) p_slc[sidx] = f2bf(es);
        if (do_w) p_swa[sidx] = f2bf(ew);
      }
    }

    // ---- PV (within-wave LDS write->read ordering; no barrier needed)
    {
      const int ridx0 = (64 * lm + 8 * hi) ^ ((lm & 7) << 3);
      bfrag pas = {}, paw = {};
      if (do_s) pas = *(const bfrag*)&p_slc[ridx0];
      if (do_w) paw = *(const bfrag*)&p_swa[ridx0];
      bfrag vb1[8];
#pragma unroll
      for (int df = 0; df < 8; ++df)
        vb1[df] = *(const bfrag*)&vtb[(size_t)(16 * df + lm) * 1024 + 32];
#pragma unroll
      for (int df = 0; df < 8; ++df) {
        if (do_s) acc_slc[df] = MFMA16(pas, vb0[df], acc_slc[df]);
        if (do_w) acc_swa[df] = MFMA16(paw, vb0[df], acc_swa[df]);
      }
      const int ridx1 = (64 * lm + 8 * hi + 32) ^ ((lm & 7) << 3);
      bfrag pas1 = {}, paw1 = {};
      if (do_s) pas1 = *(const bfrag*)&p_slc[ridx1];
      if (do_w) paw1 = *(const bfrag*)&p_swa[ridx1];
#pragma unroll
      for (int df = 0; df < 8; ++df) {
        if (do_s) acc_slc[df] = MFMA16(pas1, vb1[df], acc_slc[df]);
        if (do_w) acc_swa[df] = MFMA16(paw1, vb1[df], acc_swa[df]);
      }
    }
    ct = nct;
  }

  // ---- cross-wave combine (wave1 -> wave0) via cb overlay
  __syncthreads();
  if (wid == 1) {
    float* q = cb + l * 8;
#pragma unroll
    for (int rg = 0; rg < 4; ++rg) { q[rg] = ps_s[rg]; q[4 + rg] = ps_w[rg]; }
  }
  __syncthreads();
  if (wid == 0) {
    const float* q = cb + l * 8;
#pragma unroll
    for (int rg = 0; rg < 4; ++rg) { ps_s[rg] += q[rg]; ps_w[rg] += q[4 + rg]; }
  }
  __syncthreads();
  if (wid == 1) {
    float* q = cb + l * 32;
#pragma unroll
    for (int df = 0; df < 8; ++df)
#pragma unroll
      for (int rg = 0; rg < 4; ++rg) q[df * 4 + rg] = acc_slc[df][rg];
  }
  __syncthreads();
  if (wid == 0) {
    const float* q = cb + l * 32;
#pragma unroll
    for (int df = 0; df < 8; ++df)
#pragma unroll
      for (int rg = 0; rg < 4; ++rg) acc_slc[df][rg] += q[df * 4 + rg];
  }
  __syncthreads();
  if (wid == 1) {
    float* q = cb + l * 32;
#pragma unroll
    for (int df = 0; df < 8; ++df)
#pragma unroll
      for (int rg = 0; rg < 4; ++rg) q[df * 4 + rg] = acc_swa[df][rg];
  }
  __syncthreads();
  if (wid != 0) return;
  {
    const float* q = cb + l * 32;
#pragma unroll
    for (int df = 0; df < 8; ++df)
#pragma unroll
      for (int rg = 0; rg < 4; ++rg) acc_swa[df][rg] += q[df * 4 + rg];
  }

  // ---- compressed branch: O_cmp = Pc[16x16] * Vc[16x128], K padded to 32
  facc acc_cmp[8] = {};
  {
    bfrag pa = {};
    if (hi < 2)
      pa = *(const bfrag*)&pc[((size_t)(b * HN + h) * NSEQ + nbase + lm) * 16 + 8 * hi];
#pragma unroll
    for (int df = 0; df < 8; ++df) {
      bfrag vb = {};
      if (hi < 2)
        vb = *(const bfrag*)&vct[(((size_t)(b * HN + h) * 128) + 16 * df + lm) * 16 + 8 * hi];
      acc_cmp[df] = MFMA16(pa, vb, acc_cmp[df]);
    }
  }

  // ---- denominators: reduce across the 16 col-lanes
#pragma unroll
  for (int m = 1; m < 16; m <<= 1) {
#pragma unroll
    for (int rg = 0; rg < 4; ++rg) {
      ps_s[rg] += __shfl_xor(ps_s[rg], m);
      ps_w[rg] += __shfl_xor(ps_w[rg], m);
    }
  }

  float inv_s[4], inv_w[4], gcv[4], gsv[4], gwv[4];
#pragma unroll
  for (int rg = 0; rg < 4; ++rg) {
    inv_s[rg] = 1.0f / ps_s[rg];
    inv_w[rg] = 1.0f / ps_w[rg];
    const short* gp = qkv + (size_t)(b * NSEQ + nbase + 4 * hi + rg) * QKV_STR + GOFS;
    gcv[rg] = 1.0f / (1.0f + __expf(-bf2f(gp[h])));
    gsv[rg] = 1.0f / (1.0f + __expf(-bf2f(gp[16 + h])));
    gwv[rg] = 1.0f / (1.0f + __expf(-bf2f(gp[32 + h])));
  }

  short* obase = o + (size_t)(b * NSEQ + nbase) * 2048 + h * HDIM;
#pragma unroll
  for (int df = 0; df < 8; ++df)
#pragma unroll
    for (int rg = 0; rg < 4; ++rg) {
      float val = gcv[rg] * acc_cmp[df][rg] +
                  gsv[rg] * acc_slc[df][rg] * inv_s[rg] +
                  gwv[rg] * acc_swa[df][rg] * inv_w[rg];
      obase[(size_t)(4 * hi + rg) * 2048 + 16 * df + lm] = f2bf(val);
    }
}

// ------------------------------------------------------------------
extern "C" void kernel_launch(void* const* d_in, const int* in_sizes, int n_in,
                              void* d_out, int out_size, void* d_ws, size_t ws_size,
                              hipStream_t stream) {
  const float* x  = (const float*)d_in[0];
  const float* Wq = (const float*)d_in[1];
  const float* Wk = (const float*)d_in[2];
  const float* Wv = (const float*)d_in[3];
  const float* Wg = (const float*)d_in[4];
  const float* Wo = (const float*)d_in[5];
  float* out = (float*)d_out;

  char* w = (char*)d_ws;
  short* x_bf = (short*)w;            // 8.4 MB (reused as o_bf)
  short* o_bf = x_bf;
  w += (size_t)2048 * 2048 * 2;
  short* w_t  = (short*)w;            // 26.2 MB (rows 6272..6399 unused pad)
  w += (size_t)6400 * 2048 * 2;
  short* qkv  = (short*)w;            // 26.2 MB (stride 6400; gate at 6144)
  w += (size_t)2048 * 6400 * 2;
  float* kc   = (float*)w; w += (size_t)65536 * 4;
  short* vct  = (short*)w; w += (size_t)65536 * 2;
  short* pcb  = (short*)w; w += (size_t)524288 * 2;
  int*   sel  = (int*)w;   w += (size_t)32768 * 4;
  short* vt   = (short*)w; w += (size_t)4194304 * 2;  // 8.4 MB
  float2* tbl = (float2*)w; w += (size_t)65536 * 8;   // 0.5 MB

  const dim3 blk(256);
  prep<<<dim3(64, 64, 6), blk, 0, stream>>>(Wq, Wk, Wv, Wg, x, w_t, x_bf, tbl);
  gemm256<<<200, dim3(512), 0, stream>>>(x_bf, w_t, qkv, 2048, 6400, 2048);
  rope_qk<<<2048, blk, 0, stream>>>(qkv, tbl);
  block_mean<<<256, blk, 0, stream>>>(qkv + KOFS, kc);
  v_transpose<<<dim3(16, 16, 2), blk, 0, stream>>>(qkv, vt, vct);
  cmp_sel<<<512, dim3(64), 0, stream>>>(qkv, kc, pcb, sel);
  transpose_cast<<<dim3(64, 64), blk, 0, stream>>>(Wo, w_t);
  attn_mfma<<<2048, dim3(128), 0, stream>>>(qkv, vt, vct, pcb, sel, o_bf);
  gemm_bf16_bt<float><<<256, blk, 0, stream>>>(o_bf, w_t, out, 2048, 2048, 2048);
}